// Round 1
// baseline (1237.609 us; speedup 1.0000x reference)
//
#include <hip/hip_runtime.h>
#include <math.h>

#define B_ 2
#define T_ 2048
#define C_ 2048
#define H_ 16
#define HS_ 128
#define RHD_ 64

typedef _Float16 f16;
typedef f16 half8 __attribute__((ext_vector_type(8)));
typedef f16 half4v __attribute__((ext_vector_type(4)));
typedef f16 half2v __attribute__((ext_vector_type(2)));
typedef float f32x4 __attribute__((ext_vector_type(4)));

using gvoid_t = const __attribute__((address_space(1))) void;
using lvoid_t = __attribute__((address_space(3))) void;

#define GLOAD_LDS(gp, lp) \
  __builtin_amdgcn_global_load_lds((gvoid_t*)(gp), (lvoid_t*)(lp), 16, 0, 0)

// ---------------------------------------------------------------------------
// Batched f32 -> f16 conversion (x + 8 weights in one launch)
// ---------------------------------------------------------------------------
struct ConvBatch {
  const float* src[9];
  f16* dst[9];
  int n[9];
};

__global__ __launch_bounds__(256) void conv_f32_f16_batch(ConvBatch args) {
  const int t = blockIdx.y;
  const float* __restrict__ s = args.src[t];
  f16* __restrict__ d = args.dst[t];
  const int n4 = args.n[t] >> 2;
  for (int i = blockIdx.x * blockDim.x + threadIdx.x; i < n4;
       i += gridDim.x * blockDim.x) {
    float4 v = ((const float4*)s)[i];
    half4v h = {(f16)v.x, (f16)v.y, (f16)v.z, (f16)v.w};
    ((half4v*)d)[i] = h;
  }
}

// ---------------------------------------------------------------------------
// NT GEMM: C[M,N] = alpha * A[M,K] @ B[N,K]^T   (f16 in, f32 accum)
// 4 waves (2x2), BK=32, global_load_lds staging, 16x16x32 f16 MFMA.
// ---------------------------------------------------------------------------
template <int BM, int BN, bool OUTF32>
__global__ __launch_bounds__(256) void gemm_nt(const f16* __restrict__ A,
                                               const f16* __restrict__ Bw,
                                               void* __restrict__ Cv, int M,
                                               int N, int K, float alpha) {
  constexpr int MF = BM / 32;  // frags per wave in M
  constexpr int NF = BN / 32;  // frags per wave in N
  __shared__ f16 As[BM * 32];
  __shared__ f16 Bs[BN * 32];
  const int tid = threadIdx.x;
  const int wid = tid >> 6;
  const int lane = tid & 63;
  const int l15 = lane & 15, lg = lane >> 4;
  const int wr = wid >> 1, wc = wid & 1;
  const long bm = (long)blockIdx.y * BM;
  const long bn = (long)blockIdx.x * BN;

  const f16* Ag = A + (bm + (tid >> 2)) * (long)K + (tid & 3) * 8;
  const f16* Bg = Bw + (bn + (tid >> 2)) * (long)K + (tid & 3) * 8;
  f16* AsW = As + wid * (16 * 32);
  f16* BsW = Bs + wid * (16 * 32);

  f32x4 acc[MF][NF];
  const f32x4 zero = {0.f, 0.f, 0.f, 0.f};
#pragma unroll
  for (int m = 0; m < MF; ++m)
#pragma unroll
    for (int n = 0; n < NF; ++n) acc[m][n] = zero;

  for (int k0 = 0; k0 < K; k0 += 32) {
#pragma unroll
    for (int c = 0; c < BM / 64; ++c)
      GLOAD_LDS(Ag + (long)c * 64 * K + k0, AsW + c * 64 * 32);
#pragma unroll
    for (int c = 0; c < BN / 64; ++c)
      GLOAD_LDS(Bg + (long)c * 64 * K + k0, BsW + c * 64 * 32);
    __syncthreads();
    half8 af[MF], bf[NF];
#pragma unroll
    for (int m = 0; m < MF; ++m)
      af[m] = *(const half8*)&As[(wr * (BM / 2) + m * 16 + l15) * 32 + lg * 8];
#pragma unroll
    for (int n = 0; n < NF; ++n)
      bf[n] = *(const half8*)&Bs[(wc * (BN / 2) + n * 16 + l15) * 32 + lg * 8];
#pragma unroll
    for (int m = 0; m < MF; ++m)
#pragma unroll
      for (int n = 0; n < NF; ++n)
        acc[m][n] =
            __builtin_amdgcn_mfma_f32_16x16x32_f16(af[m], bf[n], acc[m][n], 0, 0, 0);
    __syncthreads();
  }

#pragma unroll
  for (int m = 0; m < MF; ++m) {
#pragma unroll
    for (int n = 0; n < NF; ++n) {
#pragma unroll
      for (int r = 0; r < 4; ++r) {
        long row = bm + wr * (BM / 2) + m * 16 + lg * 4 + r;
        long col = bn + wc * (BN / 2) + n * 16 + l15;
        float v = acc[m][n][r] * alpha;
        if constexpr (OUTF32)
          ((float*)Cv)[row * N + col] = v;
        else
          ((f16*)Cv)[row * N + col] = (f16)v;
      }
    }
  }
}

// ---------------------------------------------------------------------------
// RoPE (pairs interleaved); q variant applies softmax scale too.
// ---------------------------------------------------------------------------
__global__ __launch_bounds__(256) void rope_q_kernel(
    const f16* __restrict__ src, const float* __restrict__ cs,
    const float* __restrict__ sn, f16* __restrict__ dst, float scale) {
  int idx = blockIdx.x * blockDim.x + threadIdx.x;
  if (idx >= B_ * T_ * H_ * 32) return;
  int j = idx & 31;
  int t = (idx >> 9) & (T_ - 1);  // (b,t,h,pair): 32*16 = 512 per t
  half2v v = *(const half2v*)(src + (size_t)idx * 2);
  float c = cs[t * 32 + j], s = sn[t * 32 + j];
  float re = (float)v[0], im = (float)v[1];
  half2v o2 = {(f16)((re * c - im * s) * scale),
               (f16)((re * s + im * c) * scale)};
  *(half2v*)(dst + (size_t)idx * 2) = o2;
}

__global__ __launch_bounds__(256) void rope_k_kernel(
    const f16* __restrict__ src, const float* __restrict__ cs,
    const float* __restrict__ sn, f16* __restrict__ dst) {
  int idx = blockIdx.x * blockDim.x + threadIdx.x;
  if (idx >= B_ * T_ * 32) return;
  int j = idx & 31;
  int t = (idx >> 5) & (T_ - 1);
  half2v v = *(const half2v*)(src + (size_t)idx * 2);
  float c = cs[t * 32 + j], s = sn[t * 32 + j];
  float re = (float)v[0], im = (float)v[1];
  half2v o2 = {(f16)(re * c - im * s), (f16)(re * s + im * c)};
  *(half2v*)(dst + (size_t)idx * 2) = o2;
}

// ---------------------------------------------------------------------------
// V transpose: (B,T,H,128) -> (B,H,128,T), 64x64 tiles, XOR-swizzled LDS.
// ---------------------------------------------------------------------------
__global__ __launch_bounds__(256) void transpose_v_kernel(
    const f16* __restrict__ v, f16* __restrict__ vt) {
  __shared__ f16 tile[64][64];
  const int t0 = blockIdx.x * 64, d0 = blockIdx.y * 64;
  const int bh = blockIdx.z, b = bh >> 4, h = bh & 15;
  const int rr = threadIdx.x >> 3, cc = (threadIdx.x & 7) * 8;
#pragma unroll
  for (int p = 0; p < 2; ++p) {
    int r = rr + p * 32;
    int sc = (((cc >> 3) ^ ((r >> 3) & 7)) << 3);
    *(half8*)&tile[r][sc] =
        *(const half8*)&v[(((size_t)(b * T_ + t0 + r) * H_ + h) * HS_) + d0 + cc];
  }
  __syncthreads();
#pragma unroll
  for (int p = 0; p < 2; ++p) {
    int d = rr + p * 32;
    half8 o;
#pragma unroll
    for (int jj = 0; jj < 8; ++jj) {
      int row = cc + jj;
      o[jj] = tile[row][((((d >> 3) ^ ((row >> 3) & 7)) << 3) | (d & 7))];
    }
    *(half8*)&vt[((size_t)bh * HS_ + d0 + d) * T_ + t0 + cc] = o;
  }
}

// ---------------------------------------------------------------------------
// Causal flash attention. Grid (T/64, B*H), 4 waves; each wave owns a 16-row
// Q strip, iterates 64-key tiles with online softmax (f32), P via LDS.
// Q is pre-scaled by 1/sqrt(192).
// ---------------------------------------------------------------------------
__global__ __launch_bounds__(256) void attn_fwd(
    const f16* __restrict__ qc, const f16* __restrict__ qr,
    const f16* __restrict__ kc, const f16* __restrict__ kr,
    const f16* __restrict__ vt, f16* __restrict__ outp) {
  __shared__ f16 P[4][16][80];  // per-wave P tile, padded stride 80 (16B align)
  const int tid = threadIdx.x;
  const int wid = tid >> 6, lane = tid & 63;
  const int l15 = lane & 15, lg = lane >> 4;
  const int bh = blockIdx.y, b = bh >> 4, h = bh & 15;
  const int qtile = gridDim.x - 1 - blockIdx.x;  // heavy tiles first
  const int qs = qtile * 64 + wid * 16;

  const f32x4 zero = {0.f, 0.f, 0.f, 0.f};
  half8 qf[6];
  {
    const size_t bq = (size_t)(b * T_ + qs + l15);
    const f16* pc = qc + bq * C_ + h * HS_ + lg * 8;
#pragma unroll
    for (int ks = 0; ks < 4; ++ks) qf[ks] = *(const half8*)(pc + ks * 32);
    const f16* pr = qr + bq * (H_ * RHD_) + h * RHD_ + lg * 8;
#pragma unroll
    for (int ks = 0; ks < 2; ++ks) qf[4 + ks] = *(const half8*)(pr + ks * 32);
  }
  f32x4 o[8];
#pragma unroll
  for (int n = 0; n < 8; ++n) o[n] = zero;
  float m_r[4], l_r[4];
#pragma unroll
  for (int r = 0; r < 4; ++r) {
    m_r[r] = -3e38f;
    l_r[r] = 0.f;
  }

  const f16* Vb = vt + (size_t)bh * HS_ * T_;
  const int kend = qs + 16;
  for (int kt = 0; kt < kend; kt += 64) {
    f32x4 s[4];
#pragma unroll
    for (int n = 0; n < 4; ++n) s[n] = zero;
    // S = Q K^T over 64 keys, D=192 (128 from k_c, 64 from k_r)
#pragma unroll
    for (int n = 0; n < 4; ++n) {
      const size_t bk = (size_t)(b * T_ + kt + n * 16 + l15);
      const f16* pkc = kc + bk * C_ + h * HS_ + lg * 8;
#pragma unroll
      for (int ks = 0; ks < 4; ++ks) {
        half8 kf = *(const half8*)(pkc + ks * 32);
        s[n] = __builtin_amdgcn_mfma_f32_16x16x32_f16(qf[ks], kf, s[n], 0, 0, 0);
      }
      const f16* pkr = kr + bk * RHD_ + lg * 8;
#pragma unroll
      for (int ks = 0; ks < 2; ++ks) {
        half8 kf = *(const half8*)(pkr + ks * 32);
        s[n] =
            __builtin_amdgcn_mfma_f32_16x16x32_f16(qf[4 + ks], kf, s[n], 0, 0, 0);
      }
    }
    // causal mask (only boundary tiles need it)
    if (kt + 63 > qs) {
#pragma unroll
      for (int n = 0; n < 4; ++n) {
        int kcol = kt + n * 16 + l15;
#pragma unroll
        for (int r = 0; r < 4; ++r) {
          int qrow = qs + lg * 4 + r;
          if (kcol > qrow) s[n][r] = -1e30f;
        }
      }
    }
    // online softmax
    float corr[4];
#pragma unroll
    for (int r = 0; r < 4; ++r) {
      float mx = fmaxf(fmaxf(s[0][r], s[1][r]), fmaxf(s[2][r], s[3][r]));
      mx = fmaxf(mx, __shfl_xor(mx, 1));
      mx = fmaxf(mx, __shfl_xor(mx, 2));
      mx = fmaxf(mx, __shfl_xor(mx, 4));
      mx = fmaxf(mx, __shfl_xor(mx, 8));
      float mn = fmaxf(m_r[r], mx);
      corr[r] = __expf(m_r[r] - mn);
      m_r[r] = mn;
    }
    float psum[4] = {0.f, 0.f, 0.f, 0.f};
#pragma unroll
    for (int n = 0; n < 4; ++n) {
#pragma unroll
      for (int r = 0; r < 4; ++r) {
        float p = __expf(s[n][r] - m_r[r]);
        psum[r] += p;
        P[wid][lg * 4 + r][n * 16 + l15] = (f16)p;
      }
    }
#pragma unroll
    for (int r = 0; r < 4; ++r) {
      float ps = psum[r];
      ps += __shfl_xor(ps, 1);
      ps += __shfl_xor(ps, 2);
      ps += __shfl_xor(ps, 4);
      ps += __shfl_xor(ps, 8);
      l_r[r] = l_r[r] * corr[r] + ps;
    }
#pragma unroll
    for (int n = 0; n < 8; ++n)
#pragma unroll
      for (int r = 0; r < 4; ++r) o[n][r] *= corr[r];
    // O += P @ V  (V^T layout: (d, t), NT form)
#pragma unroll
    for (int kk = 0; kk < 2; ++kk) {
      half8 pa = *(const half8*)&P[wid][l15][kk * 32 + lg * 8];
      const f16* pv = Vb + (size_t)l15 * T_ + kt + kk * 32 + lg * 8;
#pragma unroll
      for (int n = 0; n < 8; ++n) {
        half8 vb = *(const half8*)(pv + (size_t)n * 16 * T_);
        o[n] = __builtin_amdgcn_mfma_f32_16x16x32_f16(pa, vb, o[n], 0, 0, 0);
      }
    }
  }
  // epilogue: O / l -> out (b,t,h,d) = (4096, 2048) f16
#pragma unroll
  for (int r = 0; r < 4; ++r) {
    float inv = 1.f / l_r[r];
    size_t rowb = ((size_t)(b * T_ + qs + lg * 4 + r)) * C_ + h * HS_ + l15;
#pragma unroll
    for (int n = 0; n < 8; ++n) outp[rowb + n * 16] = (f16)(o[n][r] * inv);
  }
}

// ---------------------------------------------------------------------------
extern "C" void kernel_launch(void* const* d_in, const int* in_sizes, int n_in,
                              void* d_out, int out_size, void* d_ws,
                              size_t ws_size, hipStream_t stream) {
  const float* x = (const float*)d_in[0];
  const float* fcos = (const float*)d_in[1];
  const float* fsin = (const float*)d_in[2];
  const float* W_dq = (const float*)d_in[3];
  const float* W_uq = (const float*)d_in[4];
  const float* W_dkv = (const float*)d_in[5];
  const float* W_uk = (const float*)d_in[6];
  const float* W_uv = (const float*)d_in[7];
  const float* W_qr = (const float*)d_in[8];
  const float* W_kr = (const float*)d_in[9];
  const float* W_o = (const float*)d_in[10];

  char* ws = (char*)d_ws;
  size_t off = 0;
  auto alc = [&](size_t elems) {
    f16* p = (f16*)(ws + off);
    off += ((elems * 2 + 255) & ~(size_t)255);
    return p;
  };
  const size_t MT = (size_t)B_ * T_;  // 4096
  f16* xb = alc(MT * 2048);
  f16* wdq = alc((size_t)512 * 2048);
  f16* wuq = alc((size_t)2048 * 512);
  f16* wdkv = alc((size_t)512 * 2048);
  f16* wuk = alc((size_t)2048 * 512);
  f16* wuv = alc((size_t)2048 * 512);
  f16* wqr = alc((size_t)1024 * 512);
  f16* wkr = alc((size_t)64 * 2048);
  f16* wo = alc((size_t)2048 * 2048);
  f16* c_q = alc(MT * 512);
  f16* c_kv = alc(MT * 512);
  f16* q_cb = alc(MT * 2048);
  f16* qr_raw = alc(MT * 1024);
  f16* q_rb = alc(MT * 1024);
  f16* k_cb = alc(MT * 2048);
  f16* kr_raw = alc(MT * 64);
  f16* k_rb = alc(MT * 64);
  f16* vb = alc(MT * 2048);
  f16* vtb = alc(MT * 2048);
  f16* aout = alc(MT * 2048);

  ConvBatch cb;
  cb.src[0] = x;     cb.dst[0] = xb;   cb.n[0] = (int)(MT * 2048);
  cb.src[1] = W_dq;  cb.dst[1] = wdq;  cb.n[1] = 512 * 2048;
  cb.src[2] = W_uq;  cb.dst[2] = wuq;  cb.n[2] = 2048 * 512;
  cb.src[3] = W_dkv; cb.dst[3] = wdkv; cb.n[3] = 512 * 2048;
  cb.src[4] = W_uk;  cb.dst[4] = wuk;  cb.n[4] = 2048 * 512;
  cb.src[5] = W_uv;  cb.dst[5] = wuv;  cb.n[5] = 2048 * 512;
  cb.src[6] = W_qr;  cb.dst[6] = wqr;  cb.n[6] = 1024 * 512;
  cb.src[7] = W_kr;  cb.dst[7] = wkr;  cb.n[7] = 64 * 2048;
  cb.src[8] = W_o;   cb.dst[8] = wo;   cb.n[8] = 2048 * 2048;
  conv_f32_f16_batch<<<dim3(128, 9), 256, 0, stream>>>(cb);

  const float scale = 0.07216878364870323f;  // 1/sqrt(192)

  // down projections (K=2048)
  gemm_nt<128, 128, false><<<dim3(4, 32), 256, 0, stream>>>(
      xb, wdq, c_q, 4096, 512, 2048, 1.f);
  gemm_nt<128, 128, false><<<dim3(4, 32), 256, 0, stream>>>(
      xb, wdkv, c_kv, 4096, 512, 2048, 1.f);
  gemm_nt<64, 64, false><<<dim3(1, 64), 256, 0, stream>>>(
      xb, wkr, kr_raw, 4096, 64, 2048, 1.f);
  // up projections (K=512); q_c pre-scaled by softmax scale
  gemm_nt<128, 128, false><<<dim3(16, 32), 256, 0, stream>>>(
      c_q, wuq, q_cb, 4096, 2048, 512, scale);
  gemm_nt<128, 128, false><<<dim3(8, 32), 256, 0, stream>>>(
      c_q, wqr, qr_raw, 4096, 1024, 512, 1.f);
  gemm_nt<128, 128, false><<<dim3(16, 32), 256, 0, stream>>>(
      c_kv, wuk, k_cb, 4096, 2048, 512, 1.f);
  gemm_nt<128, 128, false><<<dim3(16, 32), 256, 0, stream>>>(
      c_kv, wuv, vb, 4096, 2048, 512, 1.f);

  rope_q_kernel<<<(B_ * T_ * H_ * 32) / 256, 256, 0, stream>>>(
      qr_raw, fcos, fsin, q_rb, scale);
  rope_k_kernel<<<(B_ * T_ * 32) / 256, 256, 0, stream>>>(kr_raw, fcos, fsin,
                                                          k_rb);
  transpose_v_kernel<<<dim3(T_ / 64, 2, B_ * H_), 256, 0, stream>>>(vb, vtb);

  attn_fwd<<<dim3(T_ / 64, B_ * H_), 256, 0, stream>>>(q_cb, q_rb, k_cb, k_rb,
                                                       vtb, aout);

  gemm_nt<128, 128, true><<<dim3(16, 32), 256, 0, stream>>>(
      aout, wo, d_out, 4096, 2048, 2048, 1.f);
}

// Round 2
// 769.259 us; speedup vs baseline: 1.6088x; 1.6088x over previous
//
#include <hip/hip_runtime.h>
#include <math.h>

#define B_ 2
#define T_ 2048
#define C_ 2048
#define H_ 16
#define HS_ 128
#define RHD_ 64

typedef _Float16 f16;
typedef f16 half8 __attribute__((ext_vector_type(8)));
typedef f16 half4v __attribute__((ext_vector_type(4)));
typedef f16 half2v __attribute__((ext_vector_type(2)));
typedef float f32x4 __attribute__((ext_vector_type(4)));

using gvoid_t = const __attribute__((address_space(1))) void;
using lvoid_t = __attribute__((address_space(3))) void;

#define GLOAD_LDS(gp, lp) \
  __builtin_amdgcn_global_load_lds((gvoid_t*)(gp), (lvoid_t*)(lp), 16, 0, 0)

// ---------------------------------------------------------------------------
// Batched f32 -> f16 conversion (x + 8 weights in one launch)
// ---------------------------------------------------------------------------
struct ConvBatch {
  const float* src[9];
  f16* dst[9];
  int n[9];
};

__global__ __launch_bounds__(256) void conv_f32_f16_batch(ConvBatch args) {
  const int t = blockIdx.y;
  const float* __restrict__ s = args.src[t];
  f16* __restrict__ d = args.dst[t];
  const int n4 = args.n[t] >> 2;
  for (int i = blockIdx.x * blockDim.x + threadIdx.x; i < n4;
       i += gridDim.x * blockDim.x) {
    float4 v = ((const float4*)s)[i];
    half4v h = {(f16)v.x, (f16)v.y, (f16)v.z, (f16)v.w};
    ((half4v*)d)[i] = h;
  }
}

// ---------------------------------------------------------------------------
// NT GEMM: C[M,N] = alpha * A[M,K] @ B[N,K]^T   (f16 in, f32 accum)
// ---------------------------------------------------------------------------
template <int BM, int BN, bool OUTF32>
__global__ __launch_bounds__(256) void gemm_nt(const f16* __restrict__ A,
                                               const f16* __restrict__ Bw,
                                               void* __restrict__ Cv, int M,
                                               int N, int K, float alpha) {
  constexpr int MF = BM / 32;
  constexpr int NF = BN / 32;
  __shared__ f16 As[BM * 32];
  __shared__ f16 Bs[BN * 32];
  const int tid = threadIdx.x;
  const int wid = tid >> 6;
  const int lane = tid & 63;
  const int l15 = lane & 15, lg = lane >> 4;
  const int wr = wid >> 1, wc = wid & 1;
  const long bm = (long)blockIdx.y * BM;
  const long bn = (long)blockIdx.x * BN;

  const f16* Ag = A + (bm + (tid >> 2)) * (long)K + (tid & 3) * 8;
  const f16* Bg = Bw + (bn + (tid >> 2)) * (long)K + (tid & 3) * 8;
  f16* AsW = As + wid * (16 * 32);
  f16* BsW = Bs + wid * (16 * 32);

  f32x4 acc[MF][NF];
  const f32x4 zero = {0.f, 0.f, 0.f, 0.f};
#pragma unroll
  for (int m = 0; m < MF; ++m)
#pragma unroll
    for (int n = 0; n < NF; ++n) acc[m][n] = zero;

  for (int k0 = 0; k0 < K; k0 += 32) {
#pragma unroll
    for (int c = 0; c < BM / 64; ++c)
      GLOAD_LDS(Ag + (long)c * 64 * K + k0, AsW + c * 64 * 32);
#pragma unroll
    for (int c = 0; c < BN / 64; ++c)
      GLOAD_LDS(Bg + (long)c * 64 * K + k0, BsW + c * 64 * 32);
    __syncthreads();
    half8 af[MF], bf[NF];
#pragma unroll
    for (int m = 0; m < MF; ++m)
      af[m] = *(const half8*)&As[(wr * (BM / 2) + m * 16 + l15) * 32 + lg * 8];
#pragma unroll
    for (int n = 0; n < NF; ++n)
      bf[n] = *(const half8*)&Bs[(wc * (BN / 2) + n * 16 + l15) * 32 + lg * 8];
#pragma unroll
    for (int m = 0; m < MF; ++m)
#pragma unroll
      for (int n = 0; n < NF; ++n)
        acc[m][n] =
            __builtin_amdgcn_mfma_f32_16x16x32_f16(af[m], bf[n], acc[m][n], 0, 0, 0);
    __syncthreads();
  }

#pragma unroll
  for (int m = 0; m < MF; ++m) {
#pragma unroll
    for (int n = 0; n < NF; ++n) {
#pragma unroll
      for (int r = 0; r < 4; ++r) {
        long row = bm + wr * (BM / 2) + m * 16 + lg * 4 + r;
        long col = bn + wc * (BN / 2) + n * 16 + l15;
        float v = acc[m][n][r] * alpha;
        if constexpr (OUTF32)
          ((float*)Cv)[row * N + col] = v;
        else
          ((f16*)Cv)[row * N + col] = (f16)v;
      }
    }
  }
}

// ---------------------------------------------------------------------------
// RoPE
// ---------------------------------------------------------------------------
__global__ __launch_bounds__(256) void rope_q_kernel(
    const f16* __restrict__ src, const float* __restrict__ cs,
    const float* __restrict__ sn, f16* __restrict__ dst, float scale) {
  int idx = blockIdx.x * blockDim.x + threadIdx.x;
  if (idx >= B_ * T_ * H_ * 32) return;
  int j = idx & 31;
  int t = (idx >> 9) & (T_ - 1);
  half2v v = *(const half2v*)(src + (size_t)idx * 2);
  float c = cs[t * 32 + j], s = sn[t * 32 + j];
  float re = (float)v[0], im = (float)v[1];
  half2v o2 = {(f16)((re * c - im * s) * scale),
               (f16)((re * s + im * c) * scale)};
  *(half2v*)(dst + (size_t)idx * 2) = o2;
}

__global__ __launch_bounds__(256) void rope_k_kernel(
    const f16* __restrict__ src, const float* __restrict__ cs,
    const float* __restrict__ sn, f16* __restrict__ dst) {
  int idx = blockIdx.x * blockDim.x + threadIdx.x;
  if (idx >= B_ * T_ * 32) return;
  int j = idx & 31;
  int t = (idx >> 5) & (T_ - 1);
  half2v v = *(const half2v*)(src + (size_t)idx * 2);
  float c = cs[t * 32 + j], s = sn[t * 32 + j];
  float re = (float)v[0], im = (float)v[1];
  half2v o2 = {(f16)(re * c - im * s), (f16)(re * s + im * c)};
  *(half2v*)(dst + (size_t)idx * 2) = o2;
}

// ---------------------------------------------------------------------------
// V transpose: (B,T,H,128) -> (B,H,128,T)
// ---------------------------------------------------------------------------
__global__ __launch_bounds__(256) void transpose_v_kernel(
    const f16* __restrict__ v, f16* __restrict__ vt) {
  __shared__ f16 tile[64][64];
  const int t0 = blockIdx.x * 64, d0 = blockIdx.y * 64;
  const int bh = blockIdx.z, b = bh >> 4, h = bh & 15;
  const int rr = threadIdx.x >> 3, cc = (threadIdx.x & 7) * 8;
#pragma unroll
  for (int p = 0; p < 2; ++p) {
    int r = rr + p * 32;
    int sc = (((cc >> 3) ^ ((r >> 3) & 7)) << 3);
    *(half8*)&tile[r][sc] =
        *(const half8*)&v[(((size_t)(b * T_ + t0 + r) * H_ + h) * HS_) + d0 + cc];
  }
  __syncthreads();
#pragma unroll
  for (int p = 0; p < 2; ++p) {
    int d = rr + p * 32;
    half8 o;
#pragma unroll
    for (int jj = 0; jj < 8; ++jj) {
      int row = cc + jj;
      o[jj] = tile[row][((((d >> 3) ^ ((row >> 3) & 7)) << 3) | (d & 7))];
    }
    *(half8*)&vt[((size_t)bh * HS_ + d0 + d) * T_ + t0 + cc] = o;
  }
}

// ---------------------------------------------------------------------------
// Causal flash attention, LDS-staged K/V.
// Grid (T/64, B*H), 4 waves; each wave owns 16 q-rows. Block stages each
// 64-key tile (K_c 16KB, K_r 8KB, V 16KB) via global_load_lds with
// XOR-swizzled content (pre-swizzled global source, swizzled ds_read).
// Q pre-scaled by 1/sqrt(192).
// ---------------------------------------------------------------------------
__global__ __launch_bounds__(256) void attn_fwd(
    const f16* __restrict__ qc, const f16* __restrict__ qr,
    const f16* __restrict__ kc, const f16* __restrict__ kr,
    const f16* __restrict__ vt, f16* __restrict__ outp) {
  __shared__ f16 KcS[64 * 128];   // 16 KB, rowbytes 256
  __shared__ f16 KrS[64 * 64];    // 8 KB, rowbytes 128
  __shared__ f16 VsS[128 * 64];   // 16 KB, rowbytes 128
  __shared__ f16 P[4][16][88];    // per-wave P tile, stride 176B (2-way free)

  const int tid = threadIdx.x;
  const int wid = tid >> 6, lane = tid & 63;
  const int l15 = lane & 15, lg = lane >> 4;
  const int bh = blockIdx.y, b = bh >> 4, h = bh & 15;
  const int qtile = gridDim.x - 1 - blockIdx.x;  // heavy tiles first
  const int qs = qtile * 64 + wid * 16;
  const size_t bT = (size_t)b * T_;

  const f32x4 zero = {0.f, 0.f, 0.f, 0.f};
  half8 qf[6];
  {
    const size_t bq = bT + qs + l15;
    const f16* pc = qc + bq * C_ + h * HS_ + lg * 8;
#pragma unroll
    for (int ks = 0; ks < 4; ++ks) qf[ks] = *(const half8*)(pc + ks * 32);
    const f16* pr = qr + bq * (H_ * RHD_) + h * RHD_ + lg * 8;
#pragma unroll
    for (int ks = 0; ks < 2; ++ks) qf[4 + ks] = *(const half8*)(pr + ks * 32);
  }
  f32x4 o[8];
#pragma unroll
  for (int n = 0; n < 8; ++n) o[n] = zero;
  float m_r[4], l_r[4];
#pragma unroll
  for (int r = 0; r < 4; ++r) {
    m_r[r] = -3e38f;
    l_r[r] = 0.f;
  }

  const f16* Vb = vt + (size_t)bh * HS_ * T_;
  const int ntiles = qtile + 1;
  const int lb = lane * 16;  // byte offset within a 1KB issue

  for (int it = 0; it < ntiles; ++it) {
    const int kt = it * 64;
    // ---- stage K_c (16 issues), K_r (8), V (16): 10 issues per wave ----
#pragma unroll
    for (int i = 0; i < 10; ++i) {
      const int g = wid * 10 + i;
      if (g < 16) {  // K_c: 64 rows x 256B
        int ofs = g * 1024 + lb;
        int row = ofs >> 8, c = ofs & 255;
        int cs = c ^ ((row & 7) << 4);
        const f16* src = kc + (bT + kt + row) * C_ + h * HS_ + (cs >> 1);
        GLOAD_LDS(src, (char*)KcS + g * 1024);
      } else if (g < 24) {  // K_r: 64 rows x 128B
        int g2 = g - 16;
        int ofs = g2 * 1024 + lb;
        int row = ofs >> 7, c = ofs & 127;
        int cs = c ^ ((row & 7) << 4);
        const f16* src = kr + (bT + kt + row) * RHD_ + (cs >> 1);
        GLOAD_LDS(src, (char*)KrS + g2 * 1024);
      } else {  // V: 128 rows x 128B (vt layout: row=d, col=t)
        int g3 = g - 24;
        int ofs = g3 * 1024 + lb;
        int row = ofs >> 7, c = ofs & 127;
        int cs = c ^ ((row & 7) << 4);
        const f16* src = Vb + (size_t)row * T_ + kt + (cs >> 1);
        GLOAD_LDS(src, (char*)VsS + g3 * 1024);
      }
    }
    __syncthreads();

    // ---- S = Q K^T ----
    f32x4 s[4];
#pragma unroll
    for (int n = 0; n < 4; ++n) s[n] = zero;
    __builtin_amdgcn_s_setprio(1);
#pragma unroll
    for (int n = 0; n < 4; ++n) {
      const int row = n * 16 + l15;
      const char* pkc = (const char*)KcS + (row << 8);
      const int sw = (row & 7) << 4;
#pragma unroll
      for (int ks = 0; ks < 4; ++ks) {
        half8 kf = *(const half8*)(pkc + ((ks * 64 + lg * 16) ^ sw));
        s[n] = __builtin_amdgcn_mfma_f32_16x16x32_f16(qf[ks], kf, s[n], 0, 0, 0);
      }
      const char* pkr = (const char*)KrS + (row << 7);
#pragma unroll
      for (int ks = 0; ks < 2; ++ks) {
        half8 kf = *(const half8*)(pkr + ((ks * 64 + lg * 16) ^ sw));
        s[n] =
            __builtin_amdgcn_mfma_f32_16x16x32_f16(qf[4 + ks], kf, s[n], 0, 0, 0);
      }
    }
    __builtin_amdgcn_s_setprio(0);

    // ---- causal mask on diagonal tile ----
    if (it == ntiles - 1) {
#pragma unroll
      for (int n = 0; n < 4; ++n) {
        int kcol = kt + n * 16 + l15;
#pragma unroll
        for (int r = 0; r < 4; ++r) {
          int qrow = qs + lg * 4 + r;
          s[n][r] = (kcol > qrow) ? -1e30f : s[n][r];
        }
      }
    }

    // ---- online softmax ----
    float corr[4];
#pragma unroll
    for (int r = 0; r < 4; ++r) {
      float mx = fmaxf(fmaxf(s[0][r], s[1][r]), fmaxf(s[2][r], s[3][r]));
      mx = fmaxf(mx, __shfl_xor(mx, 1));
      mx = fmaxf(mx, __shfl_xor(mx, 2));
      mx = fmaxf(mx, __shfl_xor(mx, 4));
      mx = fmaxf(mx, __shfl_xor(mx, 8));
      float mn = fmaxf(m_r[r], mx);
      corr[r] = __expf(m_r[r] - mn);
      m_r[r] = mn;
    }
    float psum[4] = {0.f, 0.f, 0.f, 0.f};
#pragma unroll
    for (int n = 0; n < 4; ++n) {
#pragma unroll
      for (int r = 0; r < 4; ++r) {
        float p = __expf(s[n][r] - m_r[r]);
        psum[r] += p;
        P[wid][lg * 4 + r][n * 16 + l15] = (f16)p;
      }
    }
#pragma unroll
    for (int r = 0; r < 4; ++r) {
      float ps = psum[r];
      ps += __shfl_xor(ps, 1);
      ps += __shfl_xor(ps, 2);
      ps += __shfl_xor(ps, 4);
      ps += __shfl_xor(ps, 8);
      l_r[r] = l_r[r] * corr[r] + ps;
    }
#pragma unroll
    for (int n = 0; n < 8; ++n)
#pragma unroll
      for (int r = 0; r < 4; ++r) o[n][r] *= corr[r];

    // ---- O += P @ V ----
    __builtin_amdgcn_s_setprio(1);
#pragma unroll
    for (int kk = 0; kk < 2; ++kk) {
      half8 pa = *(const half8*)&P[wid][l15][kk * 32 + lg * 8];
#pragma unroll
      for (int n = 0; n < 8; ++n) {
        const int row = n * 16 + l15;
        half8 vb = *(const half8*)((const char*)VsS + (row << 7) +
                                   ((kk * 64 + lg * 16) ^ ((row & 7) << 4)));
        o[n] = __builtin_amdgcn_mfma_f32_16x16x32_f16(pa, vb, o[n], 0, 0, 0);
      }
    }
    __builtin_amdgcn_s_setprio(0);
    __syncthreads();
  }

  // ---- epilogue ----
#pragma unroll
  for (int r = 0; r < 4; ++r) {
    float inv = 1.f / l_r[r];
    size_t rowb = ((size_t)(bT + qs + lg * 4 + r)) * C_ + h * HS_ + l15;
#pragma unroll
    for (int n = 0; n < 8; ++n) outp[rowb + n * 16] = (f16)(o[n][r] * inv);
  }
}

// ---------------------------------------------------------------------------
extern "C" void kernel_launch(void* const* d_in, const int* in_sizes, int n_in,
                              void* d_out, int out_size, void* d_ws,
                              size_t ws_size, hipStream_t stream) {
  const float* x = (const float*)d_in[0];
  const float* fcos = (const float*)d_in[1];
  const float* fsin = (const float*)d_in[2];
  const float* W_dq = (const float*)d_in[3];
  const float* W_uq = (const float*)d_in[4];
  const float* W_dkv = (const float*)d_in[5];
  const float* W_uk = (const float*)d_in[6];
  const float* W_uv = (const float*)d_in[7];
  const float* W_qr = (const float*)d_in[8];
  const float* W_kr = (const float*)d_in[9];
  const float* W_o = (const float*)d_in[10];

  char* ws = (char*)d_ws;
  size_t off = 0;
  auto alc = [&](size_t elems) {
    f16* p = (f16*)(ws + off);
    off += ((elems * 2 + 255) & ~(size_t)255);
    return p;
  };
  const size_t MT = (size_t)B_ * T_;  // 4096
  f16* xb = alc(MT * 2048);
  f16* wdq = alc((size_t)512 * 2048);
  f16* wuq = alc((size_t)2048 * 512);
  f16* wdkv = alc((size_t)512 * 2048);
  f16* wuk = alc((size_t)2048 * 512);
  f16* wuv = alc((size_t)2048 * 512);
  f16* wqr = alc((size_t)1024 * 512);
  f16* wkr = alc((size_t)64 * 2048);
  f16* wo = alc((size_t)2048 * 2048);
  f16* c_q = alc(MT * 512);
  f16* c_kv = alc(MT * 512);
  f16* q_cb = alc(MT * 2048);
  f16* qr_raw = alc(MT * 1024);
  f16* q_rb = alc(MT * 1024);
  f16* k_cb = alc(MT * 2048);
  f16* kr_raw = alc(MT * 64);
  f16* k_rb = alc(MT * 64);
  f16* vb = alc(MT * 2048);
  f16* vtb = alc(MT * 2048);
  f16* aout = alc(MT * 2048);

  ConvBatch cb;
  cb.src[0] = x;     cb.dst[0] = xb;   cb.n[0] = (int)(MT * 2048);
  cb.src[1] = W_dq;  cb.dst[1] = wdq;  cb.n[1] = 512 * 2048;
  cb.src[2] = W_uq;  cb.dst[2] = wuq;  cb.n[2] = 2048 * 512;
  cb.src[3] = W_dkv; cb.dst[3] = wdkv; cb.n[3] = 512 * 2048;
  cb.src[4] = W_uk;  cb.dst[4] = wuk;  cb.n[4] = 2048 * 512;
  cb.src[5] = W_uv;  cb.dst[5] = wuv;  cb.n[5] = 2048 * 512;
  cb.src[6] = W_qr;  cb.dst[6] = wqr;  cb.n[6] = 1024 * 512;
  cb.src[7] = W_kr;  cb.dst[7] = wkr;  cb.n[7] = 64 * 2048;
  cb.src[8] = W_o;   cb.dst[8] = wo;   cb.n[8] = 2048 * 2048;
  conv_f32_f16_batch<<<dim3(128, 9), 256, 0, stream>>>(cb);

  const float scale = 0.07216878364870323f;  // 1/sqrt(192)

  // down projections (K=2048)
  gemm_nt<128, 128, false><<<dim3(4, 32), 256, 0, stream>>>(
      xb, wdq, c_q, 4096, 512, 2048, 1.f);
  gemm_nt<128, 128, false><<<dim3(4, 32), 256, 0, stream>>>(
      xb, wdkv, c_kv, 4096, 512, 2048, 1.f);
  gemm_nt<64, 64, false><<<dim3(1, 64), 256, 0, stream>>>(
      xb, wkr, kr_raw, 4096, 64, 2048, 1.f);
  // up projections (K=512); q_c pre-scaled by softmax scale
  gemm_nt<128, 128, false><<<dim3(16, 32), 256, 0, stream>>>(
      c_q, wuq, q_cb, 4096, 2048, 512, scale);
  gemm_nt<128, 128, false><<<dim3(8, 32), 256, 0, stream>>>(
      c_q, wqr, qr_raw, 4096, 1024, 512, 1.f);
  gemm_nt<128, 128, false><<<dim3(16, 32), 256, 0, stream>>>(
      c_kv, wuk, k_cb, 4096, 2048, 512, 1.f);
  gemm_nt<128, 128, false><<<dim3(16, 32), 256, 0, stream>>>(
      c_kv, wuv, vb, 4096, 2048, 512, 1.f);

  rope_q_kernel<<<(B_ * T_ * H_ * 32) / 256, 256, 0, stream>>>(
      qr_raw, fcos, fsin, q_rb, scale);
  rope_k_kernel<<<(B_ * T_ * 32) / 256, 256, 0, stream>>>(kr_raw, fcos, fsin,
                                                          k_rb);
  transpose_v_kernel<<<dim3(T_ / 64, 2, B_ * H_), 256, 0, stream>>>(vb, vtb);

  attn_fwd<<<dim3(T_ / 64, B_ * H_), 256, 0, stream>>>(q_cb, q_rb, k_cb, k_rb,
                                                       vtb, aout);

  gemm_nt<128, 128, true><<<dim3(16, 32), 256, 0, stream>>>(
      aout, wo, d_out, 4096, 2048, 2048, 1.f);
}

// Round 4
// 559.625 us; speedup vs baseline: 2.2115x; 1.3746x over previous
//
#include <hip/hip_runtime.h>
#include <math.h>

#define B_ 2
#define T_ 2048
#define C_ 2048
#define H_ 16
#define HS_ 128
#define RHD_ 64

typedef _Float16 f16;
typedef f16 half8 __attribute__((ext_vector_type(8)));
typedef f16 half4v __attribute__((ext_vector_type(4)));
typedef f16 half2v __attribute__((ext_vector_type(2)));
typedef float f32x4 __attribute__((ext_vector_type(4)));

using gvoid_t = const __attribute__((address_space(1))) void;
using lvoid_t = __attribute__((address_space(3))) void;

#define GLOAD_LDS(gp, lp) \
  __builtin_amdgcn_global_load_lds((gvoid_t*)(gp), (lvoid_t*)(lp), 16, 0, 0)

// ---------------------------------------------------------------------------
// Batched f32 -> f16 conversion
// ---------------------------------------------------------------------------
struct ConvBatch {
  const float* src[9];
  f16* dst[9];
  int n[9];
};

__global__ __launch_bounds__(256) void conv_f32_f16_batch(ConvBatch args) {
  const int t = blockIdx.y;
  const float* __restrict__ s = args.src[t];
  f16* __restrict__ d = args.dst[t];
  const int n4 = args.n[t] >> 2;
  for (int i = blockIdx.x * blockDim.x + threadIdx.x; i < n4;
       i += gridDim.x * blockDim.x) {
    float4 v = ((const float4*)s)[i];
    half4v h = {(f16)v.x, (f16)v.y, (f16)v.z, (f16)v.w};
    ((half4v*)d)[i] = h;
  }
}

// ---------------------------------------------------------------------------
// NT GEMM: C[M,N] = alpha * A[M,K] @ B[N,K]^T
// ---------------------------------------------------------------------------
template <int BM, int BN, bool OUTF32>
__global__ __launch_bounds__(256) void gemm_nt(const f16* __restrict__ A,
                                               const f16* __restrict__ Bw,
                                               void* __restrict__ Cv, int M,
                                               int N, int K, float alpha) {
  constexpr int MF = BM / 32;
  constexpr int NF = BN / 32;
  __shared__ f16 As[BM * 32];
  __shared__ f16 Bs[BN * 32];
  const int tid = threadIdx.x;
  const int wid = tid >> 6;
  const int lane = tid & 63;
  const int l15 = lane & 15, lg = lane >> 4;
  const int wr = wid >> 1, wc = wid & 1;
  const long bm = (long)blockIdx.y * BM;
  const long bn = (long)blockIdx.x * BN;

  const f16* Ag = A + (bm + (tid >> 2)) * (long)K + (tid & 3) * 8;
  const f16* Bg = Bw + (bn + (tid >> 2)) * (long)K + (tid & 3) * 8;
  f16* AsW = As + wid * (16 * 32);
  f16* BsW = Bs + wid * (16 * 32);

  f32x4 acc[MF][NF];
  const f32x4 zero = {0.f, 0.f, 0.f, 0.f};
#pragma unroll
  for (int m = 0; m < MF; ++m)
#pragma unroll
    for (int n = 0; n < NF; ++n) acc[m][n] = zero;

  for (int k0 = 0; k0 < K; k0 += 32) {
#pragma unroll
    for (int c = 0; c < BM / 64; ++c)
      GLOAD_LDS(Ag + (long)c * 64 * K + k0, AsW + c * 64 * 32);
#pragma unroll
    for (int c = 0; c < BN / 64; ++c)
      GLOAD_LDS(Bg + (long)c * 64 * K + k0, BsW + c * 64 * 32);
    __syncthreads();
    half8 af[MF], bf[NF];
#pragma unroll
    for (int m = 0; m < MF; ++m)
      af[m] = *(const half8*)&As[(wr * (BM / 2) + m * 16 + l15) * 32 + lg * 8];
#pragma unroll
    for (int n = 0; n < NF; ++n)
      bf[n] = *(const half8*)&Bs[(wc * (BN / 2) + n * 16 + l15) * 32 + lg * 8];
#pragma unroll
    for (int m = 0; m < MF; ++m)
#pragma unroll
      for (int n = 0; n < NF; ++n)
        acc[m][n] =
            __builtin_amdgcn_mfma_f32_16x16x32_f16(af[m], bf[n], acc[m][n], 0, 0, 0);
    __syncthreads();
  }

#pragma unroll
  for (int m = 0; m < MF; ++m) {
#pragma unroll
    for (int n = 0; n < NF; ++n) {
#pragma unroll
      for (int r = 0; r < 4; ++r) {
        long row = bm + wr * (BM / 2) + m * 16 + lg * 4 + r;
        long col = bn + wc * (BN / 2) + n * 16 + l15;
        float v = acc[m][n][r] * alpha;
        if constexpr (OUTF32)
          ((float*)Cv)[row * N + col] = v;
        else
          ((f16*)Cv)[row * N + col] = (f16)v;
      }
    }
  }
}

// ---------------------------------------------------------------------------
// RoPE
// ---------------------------------------------------------------------------
__global__ __launch_bounds__(256) void rope_q_kernel(
    const f16* __restrict__ src, const float* __restrict__ cs,
    const float* __restrict__ sn, f16* __restrict__ dst, float scale) {
  int idx = blockIdx.x * blockDim.x + threadIdx.x;
  if (idx >= B_ * T_ * H_ * 32) return;
  int j = idx & 31;
  int t = (idx >> 9) & (T_ - 1);
  half2v v = *(const half2v*)(src + (size_t)idx * 2);
  float c = cs[t * 32 + j], s = sn[t * 32 + j];
  float re = (float)v[0], im = (float)v[1];
  half2v o2 = {(f16)((re * c - im * s) * scale),
               (f16)((re * s + im * c) * scale)};
  *(half2v*)(dst + (size_t)idx * 2) = o2;
}

__global__ __launch_bounds__(256) void rope_k_kernel(
    const f16* __restrict__ src, const float* __restrict__ cs,
    const float* __restrict__ sn, f16* __restrict__ dst) {
  int idx = blockIdx.x * blockDim.x + threadIdx.x;
  if (idx >= B_ * T_ * 32) return;
  int j = idx & 31;
  int t = (idx >> 5) & (T_ - 1);
  half2v v = *(const half2v*)(src + (size_t)idx * 2);
  float c = cs[t * 32 + j], s = sn[t * 32 + j];
  float re = (float)v[0], im = (float)v[1];
  half2v o2 = {(f16)(re * c - im * s), (f16)(re * s + im * c)};
  *(half2v*)(dst + (size_t)idx * 2) = o2;
}

// ---------------------------------------------------------------------------
// V transpose: (B,T,H,128) -> (B,H,128,T)
// ---------------------------------------------------------------------------
__global__ __launch_bounds__(256) void transpose_v_kernel(
    const f16* __restrict__ v, f16* __restrict__ vt) {
  __shared__ f16 tile[64][64];
  const int t0 = blockIdx.x * 64, d0 = blockIdx.y * 64;
  const int bh = blockIdx.z, b = bh >> 4, h = bh & 15;
  const int rr = threadIdx.x >> 3, cc = (threadIdx.x & 7) * 8;
#pragma unroll
  for (int p = 0; p < 2; ++p) {
    int r = rr + p * 32;
    int sc = (((cc >> 3) ^ ((r >> 3) & 7)) << 3);
    *(half8*)&tile[r][sc] =
        *(const half8*)&v[(((size_t)(b * T_ + t0 + r) * H_ + h) * HS_) + d0 + cc];
  }
  __syncthreads();
#pragma unroll
  for (int p = 0; p < 2; ++p) {
    int d = rr + p * 32;
    half8 o;
#pragma unroll
    for (int jj = 0; jj < 8; ++jj) {
      int row = cc + jj;
      o[jj] = tile[row][((((d >> 3) ^ ((row >> 3) & 7)) << 3) | (d & 7))];
    }
    *(half8*)&vt[((size_t)bh * HS_ + d0 + d) * T_ + t0 + cc] = o;
  }
}

// ---------------------------------------------------------------------------
// Causal flash attention v3.
// Grid: 512 linear blocks -> (qtile, bh) with complementary pairing.
// 4 waves x 32 q-rows = 128 q-rows per block; 32-key tiles, double-buffered
// LDS staging (issue t+1 before computing t). Swapped QK^T (S^T: q = lane&15)
// -> cheap softmax reduce + packed P stores. Q pre-scaled by 1/sqrt(192).
// ---------------------------------------------------------------------------
__global__ __launch_bounds__(256) void attn_fwd(
    const f16* __restrict__ qc, const f16* __restrict__ qr,
    const f16* __restrict__ kc, const f16* __restrict__ kr,
    const f16* __restrict__ vt, f16* __restrict__ outp) {
  __shared__ f16 KcS[2][4096];  // 32 rows x 256B, x2 buffers
  __shared__ f16 KrS[2][2048];  // 32 rows x 128B
  __shared__ f16 VsS[2][4096];  // 128 rows x 64B (V^T: d x keys)
  __shared__ f16 Ps[4][1152];   // per-wave P: 32 q x 36 f16 (72B stride)

  const int tid = threadIdx.x;
  const int wid = tid >> 6, lane = tid & 63;
  const int l15 = lane & 15, lg = lane >> 4;
  const int lid = blockIdx.x;
  const int qtile = (lid & 15) ^ (((lid >> 8) & 1) ? 15 : 0);
  const int bh = (lid >> 4) & 31;
  const int b = bh >> 4, h = bh & 15;
  const int qs = qtile * 128 + wid * 32;  // wave's first q row
  const size_t bT = (size_t)b * T_;
  const f16* Vb = vt + (size_t)bh * HS_ * T_;

  // ---- staging slot setup (5 issues/wave/tile; 20 total = 20KB) ----
  const f16* sp[5];
  long inc[5];
  char* dst0[5];
  char* dst1[5];
#pragma unroll
  for (int i = 0; i < 5; ++i) {
    const int g = wid * 5 + i;
    if (g < 8) {  // K_c: 32 rows x 256B
      int ofs = g * 1024 + lane * 16;
      int row = ofs >> 8, c = ofs & 255;
      int cs = c ^ ((row & 7) << 4);
      sp[i] = kc + (bT + row) * (long)C_ + h * HS_ + (cs >> 1);
      inc[i] = 32 * (long)C_;
      dst0[i] = (char*)KcS + g * 1024;
      dst1[i] = dst0[i] + 8192;
    } else if (g < 12) {  // K_r: 32 rows x 128B
      int g2 = g - 8;
      int ofs = g2 * 1024 + lane * 16;
      int row = ofs >> 7, c = ofs & 127;
      int cs = c ^ ((row & 7) << 4);
      sp[i] = kr + (bT + row) * (long)RHD_ + (cs >> 1);
      inc[i] = 32 * (long)RHD_;
      dst0[i] = (char*)KrS + g2 * 1024;
      dst1[i] = dst0[i] + 4096;
    } else {  // V^T: 128 rows x 64B
      int g3 = g - 12;
      int ofs = g3 * 1024 + lane * 16;
      int row = ofs >> 6, c = ofs & 63;
      int cs = c ^ ((row & 3) << 4);
      sp[i] = Vb + (long)row * T_ + (cs >> 1);
      inc[i] = 32;
      dst0[i] = (char*)VsS + g3 * 1024;
      dst1[i] = dst0[i] + 8192;
    }
  }
  auto stage = [&](int par) {
#pragma unroll
    for (int i = 0; i < 5; ++i) {
      GLOAD_LDS(sp[i], par ? dst1[i] : dst0[i]);
      sp[i] += inc[i];
    }
  };

  const int nt = 4 * (qtile + 1);
  stage(0);

  // ---- Q fragments (B-operand: rows = q, k = d) ----
  half8 qf[2][6];
#pragma unroll
  for (int b2 = 0; b2 < 2; ++b2) {
    const size_t bq = bT + qs + b2 * 16 + l15;
    const f16* pc = qc + bq * C_ + h * HS_ + lg * 8;
#pragma unroll
    for (int ks = 0; ks < 4; ++ks) qf[b2][ks] = *(const half8*)(pc + ks * 32);
    const f16* pr = qr + bq * (H_ * RHD_) + h * RHD_ + lg * 8;
#pragma unroll
    for (int ks = 0; ks < 2; ++ks)
      qf[b2][4 + ks] = *(const half8*)(pr + ks * 32);
  }

  const f32x4 zero = {0.f, 0.f, 0.f, 0.f};
  f32x4 o[2][8];
#pragma unroll
  for (int m = 0; m < 2; ++m)
#pragma unroll
    for (int n = 0; n < 8; ++n) o[m][n] = zero;
  float m_r[2] = {-3e38f, -3e38f};
  float l_r[2] = {0.f, 0.f};

  char* Pw = (char*)Ps + wid * 2304;

  __syncthreads();

  for (int it = 0; it < nt; ++it) {
    const int kt = it * 32;
    if (it + 1 < nt) stage((it + 1) & 1);

    if (kt <= qs) {
      const int cur = it & 1;
      const char* kcb = (const char*)KcS + cur * 8192;
      const char* krb = (const char*)KrS + cur * 4096;
      const char* vsb = (const char*)VsS + cur * 8192;

      // ---- S^T = K Q^T (rows = keys, cols = q) ----
      f32x4 s[2][2];
#pragma unroll
      for (int a2 = 0; a2 < 2; ++a2)
#pragma unroll
        for (int b2 = 0; b2 < 2; ++b2) s[a2][b2] = zero;
      __builtin_amdgcn_s_setprio(1);
#pragma unroll
      for (int a2 = 0; a2 < 2; ++a2) {
        const int row = a2 * 16 + l15;
        const int sw = (row & 7) << 4;
        const char* pk = kcb + (row << 8);
#pragma unroll
        for (int ks = 0; ks < 4; ++ks) {
          half8 kf = *(const half8*)(pk + ((ks * 64 + lg * 16) ^ sw));
          s[a2][0] =
              __builtin_amdgcn_mfma_f32_16x16x32_f16(kf, qf[0][ks], s[a2][0], 0, 0, 0);
          s[a2][1] =
              __builtin_amdgcn_mfma_f32_16x16x32_f16(kf, qf[1][ks], s[a2][1], 0, 0, 0);
        }
        const char* pk2 = krb + (row << 7);
#pragma unroll
        for (int ks = 0; ks < 2; ++ks) {
          half8 kf = *(const half8*)(pk2 + ((ks * 64 + lg * 16) ^ sw));
          s[a2][0] = __builtin_amdgcn_mfma_f32_16x16x32_f16(kf, qf[0][4 + ks],
                                                            s[a2][0], 0, 0, 0);
          s[a2][1] = __builtin_amdgcn_mfma_f32_16x16x32_f16(kf, qf[1][4 + ks],
                                                            s[a2][1], 0, 0, 0);
        }
      }
      __builtin_amdgcn_s_setprio(0);

      // ---- causal mask (diagonal tile only; kt == qs) ----
      if (kt == qs) {
#pragma unroll
        for (int a2 = 0; a2 < 2; ++a2)
#pragma unroll
          for (int b2 = 0; b2 < 2; ++b2)
#pragma unroll
            for (int r = 0; r < 4; ++r) {
              int key = a2 * 16 + lg * 4 + r;
              int qq = b2 * 16 + l15;
              if (key > qq) s[a2][b2][r] = -1e30f;
            }
      }

      // ---- online softmax (per q = l15; reduce in-lane + 2 shfl) ----
      float corr[2];
#pragma unroll
      for (int b2 = 0; b2 < 2; ++b2) {
        float mx = -1e30f;
#pragma unroll
        for (int a2 = 0; a2 < 2; ++a2)
#pragma unroll
          for (int r = 0; r < 4; ++r) mx = fmaxf(mx, s[a2][b2][r]);
        mx = fmaxf(mx, __shfl_xor(mx, 16));
        mx = fmaxf(mx, __shfl_xor(mx, 32));
        float mn = fmaxf(m_r[b2], mx);
        corr[b2] = __expf(m_r[b2] - mn);
        m_r[b2] = mn;
        float ps = 0.f;
#pragma unroll
        for (int a2 = 0; a2 < 2; ++a2) {
          half4v pk4;
#pragma unroll
          for (int r = 0; r < 4; ++r) {
            float p = __expf(s[a2][b2][r] - mn);
            ps += p;
            pk4[r] = (f16)p;
          }
          *(half4v*)(Pw + (b2 * 16 + l15) * 72 + a2 * 32 + lg * 8) = pk4;
        }
        ps += __shfl_xor(ps, 16);
        ps += __shfl_xor(ps, 32);
        l_r[b2] = l_r[b2] * corr[b2] + ps;
      }

      // ---- rescale O (broadcast corr from q=l15 lanes to o rows) ----
#pragma unroll
      for (int m = 0; m < 2; ++m) {
#pragma unroll
        for (int r = 0; r < 4; ++r) {
          float cb = __shfl(corr[m], (lane & 48) | (((lane >> 4) & 3) << 2) | r);
#pragma unroll
          for (int n = 0; n < 8; ++n) o[m][n][r] *= cb;
        }
      }

      // ---- O += P @ V ----
      half8 pa0 = *(const half8*)(Pw + l15 * 72 + lg * 16);
      half8 pa1 = *(const half8*)(Pw + (16 + l15) * 72 + lg * 16);
      __builtin_amdgcn_s_setprio(1);
#pragma unroll
      for (int n = 0; n < 8; ++n) {
        const int row = n * 16 + l15;
        half8 vb = *(const half8*)(vsb + (row << 6) +
                                   ((lg * 16) ^ ((row & 3) << 4)));
        o[0][n] = __builtin_amdgcn_mfma_f32_16x16x32_f16(pa0, vb, o[0][n], 0, 0, 0);
        o[1][n] = __builtin_amdgcn_mfma_f32_16x16x32_f16(pa1, vb, o[1][n], 0, 0, 0);
      }
      __builtin_amdgcn_s_setprio(0);
    }
    __syncthreads();
  }

  // ---- epilogue: O / l ----
#pragma unroll
  for (int m = 0; m < 2; ++m) {
#pragma unroll
    for (int r = 0; r < 4; ++r) {
      float lb = __shfl(l_r[m], (lane & 48) | (((lane >> 4) & 3) << 2) | r);
      float inv = 1.f / lb;
      size_t rowb = (bT + qs + m * 16 + lg * 4 + r) * (size_t)C_ + h * HS_ + l15;
#pragma unroll
      for (int n = 0; n < 8; ++n) outp[rowb + n * 16] = (f16)(o[m][n][r] * inv);
    }
  }
}

// ---------------------------------------------------------------------------
extern "C" void kernel_launch(void* const* d_in, const int* in_sizes, int n_in,
                              void* d_out, int out_size, void* d_ws,
                              size_t ws_size, hipStream_t stream) {
  const float* x = (const float*)d_in[0];
  const float* fcos = (const float*)d_in[1];
  const float* fsin = (const float*)d_in[2];
  const float* W_dq = (const float*)d_in[3];
  const float* W_uq = (const float*)d_in[4];
  const float* W_dkv = (const float*)d_in[5];
  const float* W_uk = (const float*)d_in[6];
  const float* W_uv = (const float*)d_in[7];
  const float* W_qr = (const float*)d_in[8];
  const float* W_kr = (const float*)d_in[9];
  const float* W_o = (const float*)d_in[10];

  char* ws = (char*)d_ws;
  size_t off = 0;
  auto alc = [&](size_t elems) {
    f16* p = (f16*)(ws + off);
    off += ((elems * 2 + 255) & ~(size_t)255);
    return p;
  };
  const size_t MT = (size_t)B_ * T_;  // 4096
  f16* xb = alc(MT * 2048);
  f16* wdq = alc((size_t)512 * 2048);
  f16* wuq = alc((size_t)2048 * 512);
  f16* wdkv = alc((size_t)512 * 2048);
  f16* wuk = alc((size_t)2048 * 512);
  f16* wuv = alc((size_t)2048 * 512);
  f16* wqr = alc((size_t)1024 * 512);
  f16* wkr = alc((size_t)64 * 2048);
  f16* wo = alc((size_t)2048 * 2048);
  f16* c_q = alc(MT * 512);
  f16* c_kv = alc(MT * 512);
  f16* q_cb = alc(MT * 2048);
  f16* qr_raw = alc(MT * 1024);
  f16* q_rb = alc(MT * 1024);
  f16* k_cb = alc(MT * 2048);
  f16* kr_raw = alc(MT * 64);
  f16* k_rb = alc(MT * 64);
  f16* vb = alc(MT * 2048);
  f16* vtb = alc(MT * 2048);
  f16* aout = alc(MT * 2048);

  ConvBatch cb;
  cb.src[0] = x;     cb.dst[0] = xb;   cb.n[0] = (int)(MT * 2048);
  cb.src[1] = W_dq;  cb.dst[1] = wdq;  cb.n[1] = 512 * 2048;
  cb.src[2] = W_uq;  cb.dst[2] = wuq;  cb.n[2] = 2048 * 512;
  cb.src[3] = W_dkv; cb.dst[3] = wdkv; cb.n[3] = 512 * 2048;
  cb.src[4] = W_uk;  cb.dst[4] = wuk;  cb.n[4] = 2048 * 512;
  cb.src[5] = W_uv;  cb.dst[5] = wuv;  cb.n[5] = 2048 * 512;
  cb.src[6] = W_qr;  cb.dst[6] = wqr;  cb.n[6] = 1024 * 512;
  cb.src[7] = W_kr;  cb.dst[7] = wkr;  cb.n[7] = 64 * 2048;
  cb.src[8] = W_o;   cb.dst[8] = wo;   cb.n[8] = 2048 * 2048;
  conv_f32_f16_batch<<<dim3(128, 9), 256, 0, stream>>>(cb);

  const float scale = 0.07216878364870323f;  // 1/sqrt(192)

  // down projections (K=2048)
  gemm_nt<128, 64, false><<<dim3(8, 32), 256, 0, stream>>>(
      xb, wdq, c_q, 4096, 512, 2048, 1.f);
  gemm_nt<128, 64, false><<<dim3(8, 32), 256, 0, stream>>>(
      xb, wdkv, c_kv, 4096, 512, 2048, 1.f);
  gemm_nt<64, 64, false><<<dim3(1, 64), 256, 0, stream>>>(
      xb, wkr, kr_raw, 4096, 64, 2048, 1.f);
  // up projections (K=512); q_c pre-scaled by softmax scale
  gemm_nt<128, 128, false><<<dim3(16, 32), 256, 0, stream>>>(
      c_q, wuq, q_cb, 4096, 2048, 512, scale);
  gemm_nt<128, 128, false><<<dim3(8, 32), 256, 0, stream>>>(
      c_q, wqr, qr_raw, 4096, 1024, 512, 1.f);
  gemm_nt<128, 128, false><<<dim3(16, 32), 256, 0, stream>>>(
      c_kv, wuk, k_cb, 4096, 2048, 512, 1.f);
  gemm_nt<128, 128, false><<<dim3(16, 32), 256, 0, stream>>>(
      c_kv, wuv, vb, 4096, 2048, 512, 1.f);

  rope_q_kernel<<<(B_ * T_ * H_ * 32) / 256, 256, 0, stream>>>(
      qr_raw, fcos, fsin, q_rb, scale);
  rope_k_kernel<<<(B_ * T_ * 32) / 256, 256, 0, stream>>>(kr_raw, fcos, fsin,
                                                          k_rb);
  transpose_v_kernel<<<dim3(T_ / 64, 2, B_ * H_), 256, 0, stream>>>(vb, vtb);

  attn_fwd<<<dim3(512), 256, 0, stream>>>(q_cb, q_rb, k_cb, k_rb, vtb, aout);

  gemm_nt<128, 128, true><<<dim3(16, 32), 256, 0, stream>>>(
      aout, wo, d_out, 4096, 2048, 2048, 1.f);
}

// Round 5
// 465.586 us; speedup vs baseline: 2.6582x; 1.2020x over previous
//
#include <hip/hip_runtime.h>
#include <math.h>

#define B_ 2
#define T_ 2048
#define C_ 2048
#define H_ 16
#define HS_ 128
#define RHD_ 64

typedef _Float16 f16;
typedef f16 half8 __attribute__((ext_vector_type(8)));
typedef f16 half4v __attribute__((ext_vector_type(4)));
typedef f16 half2v __attribute__((ext_vector_type(2)));
typedef float f32x4 __attribute__((ext_vector_type(4)));

using gvoid_t = const __attribute__((address_space(1))) void;
using lvoid_t = __attribute__((address_space(3))) void;

#define GLOAD_LDS(gp, lp) \
  __builtin_amdgcn_global_load_lds((gvoid_t*)(gp), (lvoid_t*)(lp), 16, 0, 0)

// ---------------------------------------------------------------------------
// Batched f32 -> f16 conversion
// ---------------------------------------------------------------------------
struct ConvBatch {
  const float* src[9];
  f16* dst[9];
  int n[9];
};

__global__ __launch_bounds__(256) void conv_f32_f16_batch(ConvBatch args) {
  const int t = blockIdx.y;
  const float* __restrict__ s = args.src[t];
  f16* __restrict__ d = args.dst[t];
  const int n4 = args.n[t] >> 2;
  for (int i = blockIdx.x * blockDim.x + threadIdx.x; i < n4;
       i += gridDim.x * blockDim.x) {
    float4 v = ((const float4*)s)[i];
    half4v h = {(f16)v.x, (f16)v.y, (f16)v.z, (f16)v.w};
    ((half4v*)d)[i] = h;
  }
}

// ---------------------------------------------------------------------------
// NT GEMM v2: C[M,N] = alpha * A[M,K] @ B[N,K]^T
// double-buffered LDS (2-phase): stage k+1 before computing k; ONE barrier
// per K-step (vmcnt+lgkm drained by __syncthreads).
// ---------------------------------------------------------------------------
template <int BM, int BN, bool OUTF32>
__global__ __launch_bounds__(256) void gemm_nt(const f16* __restrict__ A,
                                               const f16* __restrict__ Bw,
                                               void* __restrict__ Cv, int M,
                                               int N, int K, float alpha) {
  constexpr int MF = BM / 32;
  constexpr int NF = BN / 32;
  __shared__ f16 As[2][BM * 32];
  __shared__ f16 Bs[2][BN * 32];
  const int tid = threadIdx.x;
  const int wid = tid >> 6;
  const int lane = tid & 63;
  const int l15 = lane & 15, lg = lane >> 4;
  const int wr = wid >> 1, wc = wid & 1;
  const long bm = (long)blockIdx.y * BM;
  const long bn = (long)blockIdx.x * BN;

  const f16* Ag = A + (bm + (tid >> 2)) * (long)K + (tid & 3) * 8;
  const f16* Bg = Bw + (bn + (tid >> 2)) * (long)K + (tid & 3) * 8;

  auto stg = [&](int p, int k0) {
#pragma unroll
    for (int c = 0; c < BM / 64; ++c)
      GLOAD_LDS(Ag + (long)c * 64 * K + k0, &As[p][wid * 512 + c * 2048]);
#pragma unroll
    for (int c = 0; c < BN / 64; ++c)
      GLOAD_LDS(Bg + (long)c * 64 * K + k0, &Bs[p][wid * 512 + c * 2048]);
  };

  f32x4 acc[MF][NF];
  const f32x4 zero = {0.f, 0.f, 0.f, 0.f};
#pragma unroll
  for (int m = 0; m < MF; ++m)
#pragma unroll
    for (int n = 0; n < NF; ++n) acc[m][n] = zero;

  stg(0, 0);
  __syncthreads();

  int cur = 0;
  for (int k0 = 0; k0 < K; k0 += 32) {
    if (k0 + 32 < K) stg(cur ^ 1, k0 + 32);
    half8 af[MF], bf[NF];
#pragma unroll
    for (int m = 0; m < MF; ++m)
      af[m] =
          *(const half8*)&As[cur][(wr * (BM / 2) + m * 16 + l15) * 32 + lg * 8];
#pragma unroll
    for (int n = 0; n < NF; ++n)
      bf[n] =
          *(const half8*)&Bs[cur][(wc * (BN / 2) + n * 16 + l15) * 32 + lg * 8];
    __builtin_amdgcn_s_setprio(1);
#pragma unroll
    for (int m = 0; m < MF; ++m)
#pragma unroll
      for (int n = 0; n < NF; ++n)
        acc[m][n] =
            __builtin_amdgcn_mfma_f32_16x16x32_f16(af[m], bf[n], acc[m][n], 0, 0, 0);
    __builtin_amdgcn_s_setprio(0);
    __syncthreads();
    cur ^= 1;
  }

#pragma unroll
  for (int m = 0; m < MF; ++m) {
#pragma unroll
    for (int n = 0; n < NF; ++n) {
#pragma unroll
      for (int r = 0; r < 4; ++r) {
        long row = bm + wr * (BM / 2) + m * 16 + lg * 4 + r;
        long col = bn + wc * (BN / 2) + n * 16 + l15;
        float v = acc[m][n][r] * alpha;
        if constexpr (OUTF32)
          ((float*)Cv)[row * N + col] = v;
        else
          ((f16*)Cv)[row * N + col] = (f16)v;
      }
    }
  }
}

// ---------------------------------------------------------------------------
// RoPE
// ---------------------------------------------------------------------------
__global__ __launch_bounds__(256) void rope_q_kernel(
    const f16* __restrict__ src, const float* __restrict__ cs,
    const float* __restrict__ sn, f16* __restrict__ dst, float scale) {
  int idx = blockIdx.x * blockDim.x + threadIdx.x;
  if (idx >= B_ * T_ * H_ * 32) return;
  int j = idx & 31;
  int t = (idx >> 9) & (T_ - 1);
  half2v v = *(const half2v*)(src + (size_t)idx * 2);
  float c = cs[t * 32 + j], s = sn[t * 32 + j];
  float re = (float)v[0], im = (float)v[1];
  half2v o2 = {(f16)((re * c - im * s) * scale),
               (f16)((re * s + im * c) * scale)};
  *(half2v*)(dst + (size_t)idx * 2) = o2;
}

__global__ __launch_bounds__(256) void rope_k_kernel(
    const f16* __restrict__ src, const float* __restrict__ cs,
    const float* __restrict__ sn, f16* __restrict__ dst) {
  int idx = blockIdx.x * blockDim.x + threadIdx.x;
  if (idx >= B_ * T_ * 32) return;
  int j = idx & 31;
  int t = (idx >> 5) & (T_ - 1);
  half2v v = *(const half2v*)(src + (size_t)idx * 2);
  float c = cs[t * 32 + j], s = sn[t * 32 + j];
  float re = (float)v[0], im = (float)v[1];
  half2v o2 = {(f16)(re * c - im * s), (f16)(re * s + im * c)};
  *(half2v*)(dst + (size_t)idx * 2) = o2;
}

// ---------------------------------------------------------------------------
// V transpose: (B,T,H,128) -> (B,H,128,T)
// ---------------------------------------------------------------------------
__global__ __launch_bounds__(256) void transpose_v_kernel(
    const f16* __restrict__ v, f16* __restrict__ vt) {
  __shared__ f16 tile[64][64];
  const int t0 = blockIdx.x * 64, d0 = blockIdx.y * 64;
  const int bh = blockIdx.z, b = bh >> 4, h = bh & 15;
  const int rr = threadIdx.x >> 3, cc = (threadIdx.x & 7) * 8;
#pragma unroll
  for (int p = 0; p < 2; ++p) {
    int r = rr + p * 32;
    int sc = (((cc >> 3) ^ ((r >> 3) & 7)) << 3);
    *(half8*)&tile[r][sc] =
        *(const half8*)&v[(((size_t)(b * T_ + t0 + r) * H_ + h) * HS_) + d0 + cc];
  }
  __syncthreads();
#pragma unroll
  for (int p = 0; p < 2; ++p) {
    int d = rr + p * 32;
    half8 o;
#pragma unroll
    for (int jj = 0; jj < 8; ++jj) {
      int row = cc + jj;
      o[jj] = tile[row][((((d >> 3) ^ ((row >> 3) & 7)) << 3) | (d & 7))];
    }
    *(half8*)&vt[((size_t)bh * HS_ + d0 + d) * T_ + t0 + cc] = o;
  }
}

// ---------------------------------------------------------------------------
// Causal flash attention v4 — uniform-work blocks + defer-max softmax.
// Grid: 512 blocks = 32 bh x 16 pairs. Block handles qtile pair (j, 31-j)
// sequentially (QBLK=64): total work = 66 tile-iters for EVERY block.
// 4 waves x 16 q-rows; KVBLK=32 double-buffered staging; swapped QK^T
// (S^T: q = lane&15); defer-max (THR=8) skips O-rescale; l kept as per-lane
// partial, reduced once in the epilogue. Q pre-scaled by 1/sqrt(192).
// ---------------------------------------------------------------------------
__global__ __launch_bounds__(256) void attn_fwd(
    const f16* __restrict__ qc, const f16* __restrict__ qr,
    const f16* __restrict__ kc, const f16* __restrict__ kr,
    const f16* __restrict__ vt, f16* __restrict__ outp) {
  __shared__ f16 KcS[2][4096];  // 32 key-rows x 256B per buf
  __shared__ f16 KrS[2][2048];  // 32 key-rows x 128B per buf
  __shared__ f16 VsS[2][4096];  // 128 d-rows x 64B per buf (V^T)
  __shared__ f16 Ps[4][576];    // per-wave P: 16 q x 36 f16 (72B stride)

  const int tid = threadIdx.x;
  const int wid = tid >> 6, lane = tid & 63;
  const int l15 = lane & 15, lg = lane >> 4;
  const int lid = blockIdx.x;
  const int pj = lid & 15;
  const int bh = lid >> 4;
  const int b = bh >> 4, h = bh & 15;
  const size_t bT = (size_t)b * T_;
  const f16* Vb = vt + (size_t)bh * HS_ * T_;
  const f32x4 zero = {0.f, 0.f, 0.f, 0.f};

  // ---- staging descriptors (key offset 0): 5 issues/wave, 20 KB/tile ----
  const f16* sbase[5];
  long sinc[5];
  char* d0[5];
  char* d1[5];
#pragma unroll
  for (int i = 0; i < 5; ++i) {
    const int g = wid * 5 + i;
    if (g < 8) {  // K_c: 32 rows x 256B = 8KB
      int ofs = g * 1024 + lane * 16;
      int row = ofs >> 8, c = ofs & 255;
      int cs = c ^ ((row & 7) << 4);
      sbase[i] = kc + (bT + row) * (long)C_ + h * HS_ + (cs >> 1);
      sinc[i] = 32 * (long)C_;
      d0[i] = (char*)KcS[0] + g * 1024;
      d1[i] = (char*)KcS[1] + g * 1024;
    } else if (g < 12) {  // K_r: 32 rows x 128B = 4KB
      int g2 = g - 8;
      int ofs = g2 * 1024 + lane * 16;
      int row = ofs >> 7, c = ofs & 127;
      int cs = c ^ ((row & 7) << 4);
      sbase[i] = kr + (bT + row) * (long)RHD_ + (cs >> 1);
      sinc[i] = 32 * (long)RHD_;
      d0[i] = (char*)KrS[0] + g2 * 1024;
      d1[i] = (char*)KrS[1] + g2 * 1024;
    } else {  // V^T: 128 rows x 64B = 8KB
      int g3 = g - 12;
      int ofs = g3 * 1024 + lane * 16;
      int row = ofs >> 6, c = ofs & 63;
      int cs = c ^ ((row & 3) << 4);
      sbase[i] = Vb + (long)row * T_ + (cs >> 1);
      sinc[i] = 32;
      d0[i] = (char*)VsS[0] + g3 * 1024;
      d1[i] = (char*)VsS[1] + g3 * 1024;
    }
  }

  char* Pw = (char*)Ps[wid];

  for (int sidx = 0; sidx < 2; ++sidx) {
    const int qtile = sidx ? (31 - pj) : pj;
    const int qs = qtile * 64 + wid * 16;  // wave's first q row
    const int nt = 2 * qtile + 2;

    const f16* sp[5];
#pragma unroll
    for (int i = 0; i < 5; ++i) sp[i] = sbase[i];
    // stage tile 0 -> buf0
#pragma unroll
    for (int i = 0; i < 5; ++i) {
      GLOAD_LDS(sp[i], d0[i]);
      sp[i] += sinc[i];
    }

    // Q fragments (B-operand: rows = q, k = d)
    half8 qf[6];
    {
      const size_t bq = bT + qs + l15;
      const f16* pc = qc + bq * C_ + h * HS_ + lg * 8;
#pragma unroll
      for (int ks = 0; ks < 4; ++ks) qf[ks] = *(const half8*)(pc + ks * 32);
      const f16* pr = qr + bq * (H_ * RHD_) + h * RHD_ + lg * 8;
#pragma unroll
      for (int ks = 0; ks < 2; ++ks) qf[4 + ks] = *(const half8*)(pr + ks * 32);
    }

    f32x4 o[8];
#pragma unroll
    for (int n = 0; n < 8; ++n) o[n] = zero;
    float m_r = -3e38f, l_r = 0.f;

    __syncthreads();

    for (int it = 0; it < nt; ++it) {
      const int kt = it * 32;
      const int cur = it & 1;
      if (it + 1 < nt) {
#pragma unroll
        for (int i = 0; i < 5; ++i) {
          GLOAD_LDS(sp[i], cur ? d0[i] : d1[i]);
          sp[i] += sinc[i];
        }
      }

      if (kt <= qs + 15) {
        const char* kcb = (const char*)KcS[cur];
        const char* krb = (const char*)KrS[cur];
        const char* vsb = (const char*)VsS[cur];

        // ---- S^T = K Q^T (rows = keys, cols = q = l15) ----
        f32x4 s[2] = {zero, zero};
        __builtin_amdgcn_s_setprio(1);
#pragma unroll
        for (int a2 = 0; a2 < 2; ++a2) {
          const int row = a2 * 16 + l15;
          const int sw = (row & 7) << 4;
          const char* pk = kcb + (row << 8);
#pragma unroll
          for (int ks = 0; ks < 4; ++ks) {
            half8 kf = *(const half8*)(pk + ((ks * 64 + lg * 16) ^ sw));
            s[a2] = __builtin_amdgcn_mfma_f32_16x16x32_f16(kf, qf[ks], s[a2], 0, 0, 0);
          }
          const char* pk2 = krb + (row << 7);
#pragma unroll
          for (int ks = 0; ks < 2; ++ks) {
            half8 kf = *(const half8*)(pk2 + ((ks * 64 + lg * 16) ^ sw));
            s[a2] = __builtin_amdgcn_mfma_f32_16x16x32_f16(kf, qf[4 + ks], s[a2], 0,
                                                           0, 0);
          }
        }
        __builtin_amdgcn_s_setprio(0);

        // ---- causal mask (boundary tiles only) ----
        if (kt + 31 > qs) {
#pragma unroll
          for (int a2 = 0; a2 < 2; ++a2)
#pragma unroll
            for (int r = 0; r < 4; ++r) {
              int key = kt + a2 * 16 + lg * 4 + r;
              if (key > qs + l15) s[a2][r] = -1e30f;
            }
        }

        // ---- online softmax with defer-max (THR=8) ----
        float mx = fmaxf(fmaxf(fmaxf(s[0][0], s[0][1]), fmaxf(s[0][2], s[0][3])),
                         fmaxf(fmaxf(s[1][0], s[1][1]), fmaxf(s[1][2], s[1][3])));
        mx = fmaxf(mx, __shfl_xor(mx, 16));
        mx = fmaxf(mx, __shfl_xor(mx, 32));
        if (!__all(mx <= m_r + 8.f)) {
          float mn = fmaxf(m_r, mx);
          float corr = __expf(m_r - mn);
          m_r = mn;
          l_r *= corr;
#pragma unroll
          for (int r = 0; r < 4; ++r) {
            float cb =
                __shfl(corr, (lane & 48) | (((lane >> 4) & 3) << 2) | r);
#pragma unroll
            for (int n = 0; n < 8; ++n) o[n][r] *= cb;
          }
        }
        float ps = 0.f;
#pragma unroll
        for (int a2 = 0; a2 < 2; ++a2) {
          half4v p4;
#pragma unroll
          for (int r = 0; r < 4; ++r) {
            float p = __expf(s[a2][r] - m_r);
            ps += p;
            p4[r] = (f16)p;
          }
          *(half4v*)(Pw + l15 * 72 + a2 * 32 + lg * 8) = p4;
        }
        l_r += ps;  // per-lane partial; reduced in epilogue

        // ---- O += P @ V ----
        half8 pa = *(const half8*)(Pw + l15 * 72 + lg * 16);
        __builtin_amdgcn_s_setprio(1);
#pragma unroll
        for (int n = 0; n < 8; ++n) {
          const int row = n * 16 + l15;
          half8 vb = *(const half8*)(vsb + (row << 6) +
                                     ((lg * 16) ^ ((row & 3) << 4)));
          o[n] = __builtin_amdgcn_mfma_f32_16x16x32_f16(pa, vb, o[n], 0, 0, 0);
        }
        __builtin_amdgcn_s_setprio(0);
      }
      __syncthreads();
    }

    // ---- epilogue: reduce l across lg, O / l -> out ----
    float lt = l_r;
    lt += __shfl_xor(lt, 16);
    lt += __shfl_xor(lt, 32);
#pragma unroll
    for (int r = 0; r < 4; ++r) {
      float lb = __shfl(lt, (lane & 48) | (((lane >> 4) & 3) << 2) | r);
      float inv = 1.f / lb;
      size_t rowb = (bT + qs + lg * 4 + r) * (size_t)C_ + h * HS_ + l15;
#pragma unroll
      for (int n = 0; n < 8; ++n) outp[rowb + n * 16] = (f16)(o[n][r] * inv);
    }
  }
}

// ---------------------------------------------------------------------------
extern "C" void kernel_launch(void* const* d_in, const int* in_sizes, int n_in,
                              void* d_out, int out_size, void* d_ws,
                              size_t ws_size, hipStream_t stream) {
  const float* x = (const float*)d_in[0];
  const float* fcos = (const float*)d_in[1];
  const float* fsin = (const float*)d_in[2];
  const float* W_dq = (const float*)d_in[3];
  const float* W_uq = (const float*)d_in[4];
  const float* W_dkv = (const float*)d_in[5];
  const float* W_uk = (const float*)d_in[6];
  const float* W_uv = (const float*)d_in[7];
  const float* W_qr = (const float*)d_in[8];
  const float* W_kr = (const float*)d_in[9];
  const float* W_o = (const float*)d_in[10];

  char* ws = (char*)d_ws;
  size_t off = 0;
  auto alc = [&](size_t elems) {
    f16* p = (f16*)(ws + off);
    off += ((elems * 2 + 255) & ~(size_t)255);
    return p;
  };
  const size_t MT = (size_t)B_ * T_;  // 4096
  f16* xb = alc(MT * 2048);
  f16* wdq = alc((size_t)512 * 2048);
  f16* wuq = alc((size_t)2048 * 512);
  f16* wdkv = alc((size_t)512 * 2048);
  f16* wuk = alc((size_t)2048 * 512);
  f16* wuv = alc((size_t)2048 * 512);
  f16* wqr = alc((size_t)1024 * 512);
  f16* wkr = alc((size_t)64 * 2048);
  f16* wo = alc((size_t)2048 * 2048);
  f16* c_q = alc(MT * 512);
  f16* c_kv = alc(MT * 512);
  f16* q_cb = alc(MT * 2048);
  f16* qr_raw = alc(MT * 1024);
  f16* q_rb = alc(MT * 1024);
  f16* k_cb = alc(MT * 2048);
  f16* kr_raw = alc(MT * 64);
  f16* k_rb = alc(MT * 64);
  f16* vb = alc(MT * 2048);
  f16* vtb = alc(MT * 2048);
  f16* aout = alc(MT * 2048);

  ConvBatch cb;
  cb.src[0] = x;     cb.dst[0] = xb;   cb.n[0] = (int)(MT * 2048);
  cb.src[1] = W_dq;  cb.dst[1] = wdq;  cb.n[1] = 512 * 2048;
  cb.src[2] = W_uq;  cb.dst[2] = wuq;  cb.n[2] = 2048 * 512;
  cb.src[3] = W_dkv; cb.dst[3] = wdkv; cb.n[3] = 512 * 2048;
  cb.src[4] = W_uk;  cb.dst[4] = wuk;  cb.n[4] = 2048 * 512;
  cb.src[5] = W_uv;  cb.dst[5] = wuv;  cb.n[5] = 2048 * 512;
  cb.src[6] = W_qr;  cb.dst[6] = wqr;  cb.n[6] = 1024 * 512;
  cb.src[7] = W_kr;  cb.dst[7] = wkr;  cb.n[7] = 64 * 2048;
  cb.src[8] = W_o;   cb.dst[8] = wo;   cb.n[8] = 2048 * 2048;
  conv_f32_f16_batch<<<dim3(128, 9), 256, 0, stream>>>(cb);

  const float scale = 0.07216878364870323f;  // 1/sqrt(192)

  // down projections (K=2048)
  gemm_nt<128, 64, false><<<dim3(8, 32), 256, 0, stream>>>(
      xb, wdq, c_q, 4096, 512, 2048, 1.f);
  gemm_nt<128, 64, false><<<dim3(8, 32), 256, 0, stream>>>(
      xb, wdkv, c_kv, 4096, 512, 2048, 1.f);
  gemm_nt<64, 64, false><<<dim3(1, 64), 256, 0, stream>>>(
      xb, wkr, kr_raw, 4096, 64, 2048, 1.f);
  // up projections (K=512); q_c pre-scaled by softmax scale
  gemm_nt<128, 128, false><<<dim3(16, 32), 256, 0, stream>>>(
      c_q, wuq, q_cb, 4096, 2048, 512, scale);
  gemm_nt<128, 128, false><<<dim3(8, 32), 256, 0, stream>>>(
      c_q, wqr, qr_raw, 4096, 1024, 512, 1.f);
  gemm_nt<128, 128, false><<<dim3(16, 32), 256, 0, stream>>>(
      c_kv, wuk, k_cb, 4096, 2048, 512, 1.f);
  gemm_nt<128, 128, false><<<dim3(16, 32), 256, 0, stream>>>(
      c_kv, wuv, vb, 4096, 2048, 512, 1.f);

  rope_q_kernel<<<(B_ * T_ * H_ * 32) / 256, 256, 0, stream>>>(
      qr_raw, fcos, fsin, q_rb, scale);
  rope_k_kernel<<<(B_ * T_ * 32) / 256, 256, 0, stream>>>(kr_raw, fcos, fsin,
                                                          k_rb);
  transpose_v_kernel<<<dim3(T_ / 64, 2, B_ * H_), 256, 0, stream>>>(vb, vtb);

  attn_fwd<<<dim3(512), 256, 0, stream>>>(q_cb, q_rb, k_cb, k_rb, vtb, aout);

  gemm_nt<128, 128, true><<<dim3(16, 32), 256, 0, stream>>>(
      aout, wo, d_out, 4096, 2048, 2048, 1.f);
}

// Round 6
// 415.761 us; speedup vs baseline: 2.9767x; 1.1198x over previous
//
#include <hip/hip_runtime.h>
#include <math.h>

#define B_ 2
#define T_ 2048
#define C_ 2048
#define H_ 16
#define HS_ 128
#define RHD_ 64

// fused-layout constants
#define LD_DOWN 1152   // [c_q 512 | c_kv 512 | k_r 64 | pad 64]
#define LD_UPQ 3072    // [q_c 2048 | q_r_raw 1024]
#define LD_UPKV 4096   // [k_c 2048 | v 2048]

typedef _Float16 f16;
typedef f16 half8 __attribute__((ext_vector_type(8)));
typedef f16 half4v __attribute__((ext_vector_type(4)));
typedef f16 half2v __attribute__((ext_vector_type(2)));
typedef float f32x4 __attribute__((ext_vector_type(4)));

using gvoid_t = const __attribute__((address_space(1))) void;
using lvoid_t = __attribute__((address_space(3))) void;

#define GLOAD_LDS(gp, lp) \
  __builtin_amdgcn_global_load_lds((gvoid_t*)(gp), (lvoid_t*)(lp), 16, 0, 0)

// ---------------------------------------------------------------------------
// Batched f32 -> f16 conversion with per-tensor scale (x + 8 weights)
// ---------------------------------------------------------------------------
struct ConvBatch {
  const float* src[9];
  f16* dst[9];
  int n[9];
  float scl[9];
};

__global__ __launch_bounds__(256) void conv_f32_f16_batch(ConvBatch args) {
  const int t = blockIdx.y;
  const float* __restrict__ s = args.src[t];
  f16* __restrict__ d = args.dst[t];
  const float sc = args.scl[t];
  const int n4 = args.n[t] >> 2;
  for (int i = blockIdx.x * blockDim.x + threadIdx.x; i < n4;
       i += gridDim.x * blockDim.x) {
    float4 v = ((const float4*)s)[i];
    half4v h = {(f16)(v.x * sc), (f16)(v.y * sc), (f16)(v.z * sc),
                (f16)(v.w * sc)};
    ((half4v*)d)[i] = h;
  }
}

// ---------------------------------------------------------------------------
// NT GEMM: C[M,N] = A[M,K](lda) @ B[N,K]^T (ldb=K), strided C.
// 1-D grid with bijective XCD swizzle (nwg % 8 == 0). Double-buffered LDS,
// one barrier per K-step. 4 waves (2x2), BK=32, 16x16x32 f16 MFMA.
// ---------------------------------------------------------------------------
template <int BM, int BN, bool OUTF32>
__global__ __launch_bounds__(256) void gemm_nt(const f16* __restrict__ A,
                                               long lda,
                                               const f16* __restrict__ Bw,
                                               void* __restrict__ Cv, long ldc,
                                               int K, int gx) {
  constexpr int MF = BM / 32;
  constexpr int NF = BN / 32;
  __shared__ f16 As[2][BM * 32];
  __shared__ f16 Bs[2][BN * 32];
  const int tid = threadIdx.x;
  const int wid = tid >> 6;
  const int lane = tid & 63;
  const int l15 = lane & 15, lg = lane >> 4;
  const int wr = wid >> 1, wc = wid & 1;

  // bijective XCD swizzle (requires gridDim.x % 8 == 0)
  const int nwg = gridDim.x;
  const int cpx = nwg >> 3;
  const int swz = (blockIdx.x & 7) * cpx + (blockIdx.x >> 3);
  const long bm = (long)(swz / gx) * BM;
  const long bn = (long)(swz % gx) * BN;

  const f16* Ag = A + (bm + (tid >> 2)) * lda + (tid & 3) * 8;
  const f16* Bg = Bw + (bn + (tid >> 2)) * (long)K + (tid & 3) * 8;

  auto stg = [&](int p, int k0) {
#pragma unroll
    for (int c = 0; c < BM / 64; ++c)
      GLOAD_LDS(Ag + (long)c * 64 * lda + k0, &As[p][wid * 512 + c * 2048]);
#pragma unroll
    for (int c = 0; c < BN / 64; ++c)
      GLOAD_LDS(Bg + (long)c * 64 * K + k0, &Bs[p][wid * 512 + c * 2048]);
  };

  f32x4 acc[MF][NF];
  const f32x4 zero = {0.f, 0.f, 0.f, 0.f};
#pragma unroll
  for (int m = 0; m < MF; ++m)
#pragma unroll
    for (int n = 0; n < NF; ++n) acc[m][n] = zero;

  stg(0, 0);
  __syncthreads();

  int cur = 0;
  for (int k0 = 0; k0 < K; k0 += 32) {
    if (k0 + 32 < K) stg(cur ^ 1, k0 + 32);
    half8 af[MF], bf[NF];
#pragma unroll
    for (int m = 0; m < MF; ++m)
      af[m] =
          *(const half8*)&As[cur][(wr * (BM / 2) + m * 16 + l15) * 32 + lg * 8];
#pragma unroll
    for (int n = 0; n < NF; ++n)
      bf[n] =
          *(const half8*)&Bs[cur][(wc * (BN / 2) + n * 16 + l15) * 32 + lg * 8];
    __builtin_amdgcn_s_setprio(1);
#pragma unroll
    for (int m = 0; m < MF; ++m)
#pragma unroll
      for (int n = 0; n < NF; ++n)
        acc[m][n] =
            __builtin_amdgcn_mfma_f32_16x16x32_f16(af[m], bf[n], acc[m][n], 0, 0, 0);
    __builtin_amdgcn_s_setprio(0);
    __syncthreads();
    cur ^= 1;
  }

#pragma unroll
  for (int m = 0; m < MF; ++m) {
#pragma unroll
    for (int n = 0; n < NF; ++n) {
#pragma unroll
      for (int r = 0; r < 4; ++r) {
        long row = bm + wr * (BM / 2) + m * 16 + lg * 4 + r;
        long col = bn + wc * (BN / 2) + n * 16 + l15;
        float v = acc[m][n][r];
        if constexpr (OUTF32)
          ((float*)Cv)[row * ldc + col] = v;
        else
          ((f16*)Cv)[row * ldc + col] = (f16)v;
      }
    }
  }
}

// ---------------------------------------------------------------------------
// RoPE (reads strided fused GEMM outputs, writes packed)
// ---------------------------------------------------------------------------
__global__ __launch_bounds__(256) void rope_q_kernel(
    const f16* __restrict__ src, const float* __restrict__ cs,
    const float* __restrict__ sn, f16* __restrict__ dst, float scale) {
  int idx = blockIdx.x * blockDim.x + threadIdx.x;
  if (idx >= B_ * T_ * H_ * 32) return;
  int j = idx & 31;
  int ta = idx >> 9;             // absolute row (b*T + t)
  int t = ta & (T_ - 1);
  int rem = idx & 511;           // h*32 + j
  half2v v = *(const half2v*)(src + (size_t)ta * LD_UPQ + 2048 + rem * 2);
  float c = cs[t * 32 + j], s = sn[t * 32 + j];
  float re = (float)v[0], im = (float)v[1];
  half2v o2 = {(f16)((re * c - im * s) * scale),
               (f16)((re * s + im * c) * scale)};
  *(half2v*)(dst + (size_t)idx * 2) = o2;
}

__global__ __launch_bounds__(256) void rope_k_kernel(
    const f16* __restrict__ src, const float* __restrict__ cs,
    const float* __restrict__ sn, f16* __restrict__ dst) {
  int idx = blockIdx.x * blockDim.x + threadIdx.x;
  if (idx >= B_ * T_ * 32) return;
  int j = idx & 31;
  int ta = idx >> 5;
  int t = ta & (T_ - 1);
  half2v v = *(const half2v*)(src + (size_t)ta * LD_DOWN + 1024 + j * 2);
  float c = cs[t * 32 + j], s = sn[t * 32 + j];
  float re = (float)v[0], im = (float)v[1];
  half2v o2 = {(f16)(re * c - im * s), (f16)(re * s + im * c)};
  *(half2v*)(dst + (size_t)idx * 2) = o2;
}

// ---------------------------------------------------------------------------
// V transpose: reads v at cols [2048..4096) of upkv (stride 4096)
// -> vt (B,H,128,T)
// ---------------------------------------------------------------------------
__global__ __launch_bounds__(256) void transpose_v_kernel(
    const f16* __restrict__ v, f16* __restrict__ vt) {
  __shared__ f16 tile[64][64];
  const int t0 = blockIdx.x * 64, d0 = blockIdx.y * 64;
  const int bh = blockIdx.z, b = bh >> 4, h = bh & 15;
  const int rr = threadIdx.x >> 3, cc = (threadIdx.x & 7) * 8;
#pragma unroll
  for (int p = 0; p < 2; ++p) {
    int r = rr + p * 32;
    int sc = (((cc >> 3) ^ ((r >> 3) & 7)) << 3);
    *(half8*)&tile[r][sc] = *(const half8*)&v[(size_t)(b * T_ + t0 + r) *
                                                  LD_UPKV +
                                              2048 + h * HS_ + d0 + cc];
  }
  __syncthreads();
#pragma unroll
  for (int p = 0; p < 2; ++p) {
    int d = rr + p * 32;
    half8 o;
#pragma unroll
    for (int jj = 0; jj < 8; ++jj) {
      int row = cc + jj;
      o[jj] = tile[row][((((d >> 3) ^ ((row >> 3) & 7)) << 3) | (d & 7))];
    }
    *(half8*)&vt[((size_t)bh * HS_ + d0 + d) * T_ + t0 + cc] = o;
  }
}

// ---------------------------------------------------------------------------
// Causal flash attention v4 (round-5 structure, strided q_c/k_c inputs).
// ---------------------------------------------------------------------------
__global__ __launch_bounds__(256) void attn_fwd(
    const f16* __restrict__ qc, const f16* __restrict__ qr,
    const f16* __restrict__ kc, const f16* __restrict__ kr,
    const f16* __restrict__ vt, f16* __restrict__ outp) {
  __shared__ f16 KcS[2][4096];  // 32 key-rows x 256B per buf
  __shared__ f16 KrS[2][2048];  // 32 key-rows x 128B per buf
  __shared__ f16 VsS[2][4096];  // 128 d-rows x 64B per buf (V^T)
  __shared__ f16 Ps[4][576];    // per-wave P: 16 q x 36 f16 (72B stride)

  const int tid = threadIdx.x;
  const int wid = tid >> 6, lane = tid & 63;
  const int l15 = lane & 15, lg = lane >> 4;
  const int lid = blockIdx.x;
  const int pj = lid & 15;
  const int bh = lid >> 4;
  const int b = bh >> 4, h = bh & 15;
  const size_t bT = (size_t)b * T_;
  const f16* Vb = vt + (size_t)bh * HS_ * T_;
  const f32x4 zero = {0.f, 0.f, 0.f, 0.f};

  // ---- staging descriptors (key offset 0): 5 issues/wave, 20 KB/tile ----
  const f16* sbase[5];
  long sinc[5];
  char* d0[5];
  char* d1[5];
#pragma unroll
  for (int i = 0; i < 5; ++i) {
    const int g = wid * 5 + i;
    if (g < 8) {  // K_c: 32 rows x 256B = 8KB
      int ofs = g * 1024 + lane * 16;
      int row = ofs >> 8, c = ofs & 255;
      int cs = c ^ ((row & 7) << 4);
      sbase[i] = kc + (bT + row) * (long)LD_UPKV + h * HS_ + (cs >> 1);
      sinc[i] = 32 * (long)LD_UPKV;
      d0[i] = (char*)KcS[0] + g * 1024;
      d1[i] = (char*)KcS[1] + g * 1024;
    } else if (g < 12) {  // K_r: 32 rows x 128B = 4KB
      int g2 = g - 8;
      int ofs = g2 * 1024 + lane * 16;
      int row = ofs >> 7, c = ofs & 127;
      int cs = c ^ ((row & 7) << 4);
      sbase[i] = kr + (bT + row) * (long)RHD_ + (cs >> 1);
      sinc[i] = 32 * (long)RHD_;
      d0[i] = (char*)KrS[0] + g2 * 1024;
      d1[i] = (char*)KrS[1] + g2 * 1024;
    } else {  // V^T: 128 rows x 64B = 8KB
      int g3 = g - 12;
      int ofs = g3 * 1024 + lane * 16;
      int row = ofs >> 6, c = ofs & 63;
      int cs = c ^ ((row & 3) << 4);
      sbase[i] = Vb + (long)row * T_ + (cs >> 1);
      sinc[i] = 32;
      d0[i] = (char*)VsS[0] + g3 * 1024;
      d1[i] = (char*)VsS[1] + g3 * 1024;
    }
  }

  char* Pw = (char*)Ps[wid];

  for (int sidx = 0; sidx < 2; ++sidx) {
    const int qtile = sidx ? (31 - pj) : pj;
    const int qs = qtile * 64 + wid * 16;  // wave's first q row
    const int nt = 2 * qtile + 2;

    const f16* sp[5];
#pragma unroll
    for (int i = 0; i < 5; ++i) sp[i] = sbase[i];
    // stage tile 0 -> buf0
#pragma unroll
    for (int i = 0; i < 5; ++i) {
      GLOAD_LDS(sp[i], d0[i]);
      sp[i] += sinc[i];
    }

    // Q fragments (B-operand: rows = q, k = d)
    half8 qf[6];
    {
      const size_t bq = bT + qs + l15;
      const f16* pc = qc + bq * LD_UPQ + h * HS_ + lg * 8;
#pragma unroll
      for (int ks = 0; ks < 4; ++ks) qf[ks] = *(const half8*)(pc + ks * 32);
      const f16* pr = qr + bq * (H_ * RHD_) + h * RHD_ + lg * 8;
#pragma unroll
      for (int ks = 0; ks < 2; ++ks) qf[4 + ks] = *(const half8*)(pr + ks * 32);
    }

    f32x4 o[8];
#pragma unroll
    for (int n = 0; n < 8; ++n) o[n] = zero;
    float m_r = -3e38f, l_r = 0.f;

    __syncthreads();

    for (int it = 0; it < nt; ++it) {
      const int kt = it * 32;
      const int cur = it & 1;
      if (it + 1 < nt) {
#pragma unroll
        for (int i = 0; i < 5; ++i) {
          GLOAD_LDS(sp[i], cur ? d0[i] : d1[i]);
          sp[i] += sinc[i];
        }
      }

      if (kt <= qs + 15) {
        const char* kcb = (const char*)KcS[cur];
        const char* krb = (const char*)KrS[cur];
        const char* vsb = (const char*)VsS[cur];

        // ---- S^T = K Q^T (rows = keys, cols = q = l15) ----
        f32x4 s[2] = {zero, zero};
        __builtin_amdgcn_s_setprio(1);
#pragma unroll
        for (int a2 = 0; a2 < 2; ++a2) {
          const int row = a2 * 16 + l15;
          const int sw = (row & 7) << 4;
          const char* pk = kcb + (row << 8);
#pragma unroll
          for (int ks = 0; ks < 4; ++ks) {
            half8 kf = *(const half8*)(pk + ((ks * 64 + lg * 16) ^ sw));
            s[a2] = __builtin_amdgcn_mfma_f32_16x16x32_f16(kf, qf[ks], s[a2], 0, 0, 0);
          }
          const char* pk2 = krb + (row << 7);
#pragma unroll
          for (int ks = 0; ks < 2; ++ks) {
            half8 kf = *(const half8*)(pk2 + ((ks * 64 + lg * 16) ^ sw));
            s[a2] = __builtin_amdgcn_mfma_f32_16x16x32_f16(kf, qf[4 + ks], s[a2], 0,
                                                           0, 0);
          }
        }
        __builtin_amdgcn_s_setprio(0);

        // ---- causal mask (boundary tiles only) ----
        if (kt + 31 > qs) {
#pragma unroll
          for (int a2 = 0; a2 < 2; ++a2)
#pragma unroll
            for (int r = 0; r < 4; ++r) {
              int key = kt + a2 * 16 + lg * 4 + r;
              if (key > qs + l15) s[a2][r] = -1e30f;
            }
        }

        // ---- online softmax with defer-max (THR=8) ----
        float mx = fmaxf(fmaxf(fmaxf(s[0][0], s[0][1]), fmaxf(s[0][2], s[0][3])),
                         fmaxf(fmaxf(s[1][0], s[1][1]), fmaxf(s[1][2], s[1][3])));
        mx = fmaxf(mx, __shfl_xor(mx, 16));
        mx = fmaxf(mx, __shfl_xor(mx, 32));
        if (!__all(mx <= m_r + 8.f)) {
          float mn = fmaxf(m_r, mx);
          float corr = __expf(m_r - mn);
          m_r = mn;
          l_r *= corr;
#pragma unroll
          for (int r = 0; r < 4; ++r) {
            float cb =
                __shfl(corr, (lane & 48) | (((lane >> 4) & 3) << 2) | r);
#pragma unroll
            for (int n = 0; n < 8; ++n) o[n][r] *= cb;
          }
        }
        float ps = 0.f;
#pragma unroll
        for (int a2 = 0; a2 < 2; ++a2) {
          half4v p4;
#pragma unroll
          for (int r = 0; r < 4; ++r) {
            float p = __expf(s[a2][r] - m_r);
            ps += p;
            p4[r] = (f16)p;
          }
          *(half4v*)(Pw + l15 * 72 + a2 * 32 + lg * 8) = p4;
        }
        l_r += ps;  // per-lane partial; reduced in epilogue

        // ---- O += P @ V ----
        half8 pa = *(const half8*)(Pw + l15 * 72 + lg * 16);
        __builtin_amdgcn_s_setprio(1);
#pragma unroll
        for (int n = 0; n < 8; ++n) {
          const int row = n * 16 + l15;
          half8 vb = *(const half8*)(vsb + (row << 6) +
                                     ((lg * 16) ^ ((row & 3) << 4)));
          o[n] = __builtin_amdgcn_mfma_f32_16x16x32_f16(pa, vb, o[n], 0, 0, 0);
        }
        __builtin_amdgcn_s_setprio(0);
      }
      __syncthreads();
    }

    // ---- epilogue: reduce l across lg, O / l -> out ----
    float lt = l_r;
    lt += __shfl_xor(lt, 16);
    lt += __shfl_xor(lt, 32);
#pragma unroll
    for (int r = 0; r < 4; ++r) {
      float lb = __shfl(lt, (lane & 48) | (((lane >> 4) & 3) << 2) | r);
      float inv = 1.f / lb;
      size_t rowb = (bT + qs + lg * 4 + r) * (size_t)C_ + h * HS_ + l15;
#pragma unroll
      for (int n = 0; n < 8; ++n) outp[rowb + n * 16] = (f16)(o[n][r] * inv);
    }
  }
}

// ---------------------------------------------------------------------------
extern "C" void kernel_launch(void* const* d_in, const int* in_sizes, int n_in,
                              void* d_out, int out_size, void* d_ws,
                              size_t ws_size, hipStream_t stream) {
  const float* x = (const float*)d_in[0];
  const float* fcos = (const float*)d_in[1];
  const float* fsin = (const float*)d_in[2];
  const float* W_dq = (const float*)d_in[3];
  const float* W_uq = (const float*)d_in[4];
  const float* W_dkv = (const float*)d_in[5];
  const float* W_uk = (const float*)d_in[6];
  const float* W_uv = (const float*)d_in[7];
  const float* W_qr = (const float*)d_in[8];
  const float* W_kr = (const float*)d_in[9];
  const float* W_o = (const float*)d_in[10];

  char* ws = (char*)d_ws;
  size_t off = 0;
  auto alc = [&](size_t elems) {
    f16* p = (f16*)(ws + off);
    off += ((elems * 2 + 255) & ~(size_t)255);
    return p;
  };
  const size_t MT = (size_t)B_ * T_;  // 4096
  f16* xb = alc(MT * 2048);
  f16* wdown = alc((size_t)LD_DOWN * 2048);   // [W_dq;W_dkv;W_kr;pad]
  f16* wupq = alc((size_t)LD_UPQ * 512);      // [W_uq(scaled);W_qr]
  f16* wupkv = alc((size_t)LD_UPKV * 512);    // [W_uk;W_uv]
  f16* wo = alc((size_t)2048 * 2048);
  f16* cdown = alc(MT * LD_DOWN);             // [c_q|c_kv|kr_raw|pad]
  f16* upq = alc(MT * LD_UPQ);                // [q_c|qr_raw]
  f16* upkv = alc(MT * LD_UPKV);              // [k_c|v]
  f16* q_rb = alc(MT * 1024);
  f16* k_rb = alc(MT * 64);
  f16* vtb = alc(MT * 2048);
  f16* aout = alc(MT * 2048);

  const float scale = 0.07216878364870323f;  // 1/sqrt(192)

  ConvBatch cb;
  cb.src[0] = x;     cb.dst[0] = xb;                  cb.n[0] = (int)(MT * 2048); cb.scl[0] = 1.f;
  cb.src[1] = W_dq;  cb.dst[1] = wdown;               cb.n[1] = 512 * 2048;       cb.scl[1] = 1.f;
  cb.src[2] = W_dkv; cb.dst[2] = wdown + 512 * 2048;  cb.n[2] = 512 * 2048;       cb.scl[2] = 1.f;
  cb.src[3] = W_kr;  cb.dst[3] = wdown + 1024 * 2048; cb.n[3] = 64 * 2048;        cb.scl[3] = 1.f;
  cb.src[4] = W_uq;  cb.dst[4] = wupq;                cb.n[4] = 2048 * 512;       cb.scl[4] = scale;
  cb.src[5] = W_qr;  cb.dst[5] = wupq + 2048 * 512;   cb.n[5] = 1024 * 512;       cb.scl[5] = 1.f;
  cb.src[6] = W_uk;  cb.dst[6] = wupkv;               cb.n[6] = 2048 * 512;       cb.scl[6] = 1.f;
  cb.src[7] = W_uv;  cb.dst[7] = wupkv + 2048 * 512;  cb.n[7] = 2048 * 512;       cb.scl[7] = 1.f;
  cb.src[8] = W_o;   cb.dst[8] = wo;                  cb.n[8] = 2048 * 2048;      cb.scl[8] = 1.f;
  conv_f32_f16_batch<<<dim3(128, 9), 256, 0, stream>>>(cb);

  // fused down projection: x @ [W_dq;W_dkv;W_kr]^T  (cols 1088..1151 unused)
  gemm_nt<128, 128, false><<<288, 256, 0, stream>>>(xb, 2048, wdown, cdown,
                                                    LD_DOWN, 2048, 9);
  // fused up-q: c_q @ [W_uq*s;W_qr]^T
  gemm_nt<128, 128, false><<<768, 256, 0, stream>>>(cdown, LD_DOWN, wupq, upq,
                                                    LD_UPQ, 512, 24);
  // fused up-kv: c_kv @ [W_uk;W_uv]^T
  gemm_nt<128, 128, false><<<1024, 256, 0, stream>>>(cdown + 512, LD_DOWN,
                                                     wupkv, upkv, LD_UPKV, 512,
                                                     32);

  rope_q_kernel<<<(B_ * T_ * H_ * 32) / 256, 256, 0, stream>>>(
      upq, fcos, fsin, q_rb, scale);
  rope_k_kernel<<<(B_ * T_ * 32) / 256, 256, 0, stream>>>(cdown, fcos, fsin,
                                                          k_rb);
  transpose_v_kernel<<<dim3(T_ / 64, 2, B_ * H_), 256, 0, stream>>>(upkv, vtb);

  attn_fwd<<<dim3(512), 256, 0, stream>>>(upq, q_rb, upkv, k_rb, vtb, aout);

  gemm_nt<128, 128, true><<<512, 256, 0, stream>>>(aout, 2048, wo, d_out, 2048,
                                                   2048, 16);
}